// Round 1
// baseline (309.878 us; speedup 1.0000x reference)
//
#include <hip/hip_runtime.h>
#include <math.h>

#define NODES   16384
#define NGRAPH  1024
#define EDGES   245760
#define EPG     240
#define FDIM    256

#define OUT_MEAN  0
#define OUT_STD   24576
#define OUT_SCANS 49152
#define OUT_RECON 376832

static __device__ __forceinline__ float lrelu02(float v){ return v > 0.f ? v : 0.2f*v; }

// ---------------- edge_attr mean (two-stage deterministic reduction) --------
__global__ __launch_bounds__(256) void ea_partial_kernel(const float* __restrict__ ea,
                                                         float* __restrict__ partial)
{
    __shared__ float red[256];
    const int tid = threadIdx.x;
    const int base = blockIdx.x * 960;   // 256 blocks * 960 = 245760
    float s = 0.f;
    for (int i = tid; i < 960; i += 256) s += ea[base + i];
    red[tid] = s; __syncthreads();
    for (int off = 128; off > 0; off >>= 1) {
        if (tid < off) red[tid] += red[tid + off];
        __syncthreads();
    }
    if (tid == 0) partial[blockIdx.x] = red[0];
}

__global__ __launch_bounds__(256) void ea_final_kernel(const float* __restrict__ partial,
                                                       float* __restrict__ mean_out)
{
    __shared__ float red[256];
    const int tid = threadIdx.x;
    red[tid] = partial[tid]; __syncthreads();
    for (int off = 128; off > 0; off >>= 1) {
        if (tid < off) red[tid] += red[tid + off];
        __syncthreads();
    }
    if (tid == 0) mean_out[0] = red[0] * (1.f / (float)EDGES);
}

// ---------------- lidar encoder + recon (thread per node) -------------------
__global__ __launch_bounds__(256) void lidar_kernel(
    const float* __restrict__ x,
    const float* __restrict__ w1, const float* __restrict__ b1,
    const float* __restrict__ w2, const float* __restrict__ b2,
    const float* __restrict__ wl, const float* __restrict__ bl,
    const float* __restrict__ dw1, const float* __restrict__ db1,
    const float* __restrict__ dw2, const float* __restrict__ db2,
    float* __restrict__ out)
{
    // scans staged in LDS, row stride 25 (odd -> conflict-free), with zero pads
    __shared__ float sc[256][25];
    const int tid = threadIdx.x;
    const int n = blockIdx.x * 256 + tid;

    sc[tid][0] = 0.f; sc[tid][1] = 0.f;
    sc[tid][22] = 0.f; sc[tid][23] = 0.f; sc[tid][24] = 0.f;
    for (int t = 0; t < 20; ++t) {
        float v = x[n * 29 + t];
        sc[tid][t + 2] = v;
        out[OUT_SCANS + n * 20 + t] = v;   // scans output is a copy
    }
    __syncthreads();

    // streaming conv1(+relu)+maxpool2 window (pA,pB,pC) -> conv2(+relu) -> mean
    float pA[16], pB[16], pC[16];
    float macc[32];
#pragma unroll
    for (int oc = 0; oc < 32; ++oc) macc[oc] = 0.f;
#pragma unroll
    for (int ic = 0; ic < 16; ++ic) pA[ic] = 0.f;

    // pB = pooled column 0 (conv1 at positions 0 and 1); sc index = pos + k
#pragma unroll
    for (int ic = 0; ic < 16; ++ic) {
        float a = b1[ic], b = b1[ic];
#pragma unroll
        for (int k = 0; k < 5; ++k) {
            a += sc[tid][0 + k] * w1[ic * 5 + k];
            b += sc[tid][1 + k] * w1[ic * 5 + k];
        }
        pB[ic] = fmaxf(fmaxf(a, b), 0.f);
    }

    for (int t = 0; t < 10; ++t) {
        if (t < 9) {
            const int u0 = 2 * (t + 1);
#pragma unroll
            for (int ic = 0; ic < 16; ++ic) {
                float a = b1[ic], b = b1[ic];
#pragma unroll
                for (int k = 0; k < 5; ++k) {
                    a += sc[tid][u0 + k] * w1[ic * 5 + k];
                    b += sc[tid][u0 + 1 + k] * w1[ic * 5 + k];
                }
                pC[ic] = fmaxf(fmaxf(a, b), 0.f);
            }
        } else {
#pragma unroll
            for (int ic = 0; ic < 16; ++ic) pC[ic] = 0.f;
        }
#pragma unroll
        for (int oc = 0; oc < 32; ++oc) {
            float v = b2[oc];
            const float* wrow = &w2[oc * 48];
#pragma unroll
            for (int ic = 0; ic < 16; ++ic) {
                v += pA[ic] * wrow[ic * 3 + 0]
                   + pB[ic] * wrow[ic * 3 + 1]
                   + pC[ic] * wrow[ic * 3 + 2];
            }
            macc[oc] += fmaxf(v, 0.f);
        }
#pragma unroll
        for (int ic = 0; ic < 16; ++ic) { pA[ic] = pB[ic]; pB[ic] = pC[ic]; }
    }

    // z = relu(feat @ wl.T + bl), feat = macc/10
    float z[5];
#pragma unroll
    for (int j = 0; j < 5; ++j) {
        float v = bl[j];
#pragma unroll
        for (int c = 0; c < 32; ++c) v += (macc[c] * 0.1f) * wl[j * 32 + c];
        z[j] = fmaxf(v, 0.f);
    }
    // hid = relu(z @ dw1.T + db1)
    float hid[32];
#pragma unroll
    for (int k = 0; k < 32; ++k) {
        float v = db1[k];
#pragma unroll
        for (int j = 0; j < 5; ++j) v += z[j] * dw1[k * 5 + j];
        hid[k] = fmaxf(v, 0.f);
    }
    // recon = hid @ dw2.T + db2
    for (int t = 0; t < 20; ++t) {
        float v = db2[t];
#pragma unroll
        for (int k = 0; k < 32; ++k) v += hid[k] * dw2[t * 32 + k];
        out[OUT_RECON + n * 20 + t] = v;
    }
}

// ---------------- fused GAT layer: block = one graph (16 nodes) -------------
// IN_K = 6 (layer1, input = x[:,20:26], no self loops) or 256 (layers 2/3,
// input = previous h, with self loop whose attr = mean(edge_attr)).
template <int IN_K, bool SELF_LOOP>
__global__ __launch_bounds__(256) void gat_kernel(
    const float* __restrict__ hin,
    const float* __restrict__ W,       // (IN_K, 256)
    const float* __restrict__ asrc,    // (8,32)
    const float* __restrict__ adst,    // (8,32)
    const float* __restrict__ We,      // (256)
    const float* __restrict__ ae,      // (8,32)
    const float* __restrict__ bias,    // (256)
    const float* __restrict__ ea,      // (EDGES)
    const float* __restrict__ ea_mean, // 1 float
    float* __restrict__ hout)
{
    __shared__ float hs[16][IN_K];
    __shared__ float xw[16][256];
    __shared__ float coef[8][16][16];   // [h][s][d]
    __shared__ float sals[16][8], sald[16][8];
    __shared__ float sasrc[256], sadst[256], sS[8];

    const int tid = threadIdx.x;
    const int g = blockIdx.x;

    if constexpr (IN_K == 6) {
        if (tid < 96) { int i = tid / 6, k = tid % 6; hs[i][k] = hin[(g * 16 + i) * 29 + 20 + k]; }
    } else {
        for (int r = 0; r < 16; ++r) hs[r][tid] = hin[(g * 16 + r) * 256 + tid];
    }
    sasrc[tid] = asrc[tid];
    sadst[tid] = adst[tid];
    if (tid < 8) {
        float s = 0.f;
        for (int c = 0; c < 32; ++c) s += We[tid * 32 + c] * ae[tid * 32 + c];
        sS[tid] = s;
    }
    __syncthreads();

    // GEMM: xw[i][tid] = sum_k hs[i][k] * W[k][tid]
    {
        float acc[16];
#pragma unroll
        for (int i = 0; i < 16; ++i) acc[i] = 0.f;
        if constexpr (IN_K == 6) {
#pragma unroll
            for (int k = 0; k < 6; ++k) {
                float w = W[k * 256 + tid];
#pragma unroll
                for (int i = 0; i < 16; ++i) acc[i] += hs[i][k] * w;
            }
        } else {
            for (int k0 = 0; k0 < 256; k0 += 4) {
                const float w0 = W[(k0 + 0) * 256 + tid];
                const float w1v = W[(k0 + 1) * 256 + tid];
                const float w2v = W[(k0 + 2) * 256 + tid];
                const float w3v = W[(k0 + 3) * 256 + tid];
#pragma unroll
                for (int i = 0; i < 16; ++i) {
                    const float4 h4 = *reinterpret_cast<const float4*>(&hs[i][k0]);
                    acc[i] += h4.x * w0 + h4.y * w1v + h4.z * w2v + h4.w * w3v;
                }
            }
        }
#pragma unroll
        for (int i = 0; i < 16; ++i) xw[i][tid] = acc[i];
    }
    __syncthreads();

    // als/ald per (node, head)
    if (tid < 128) {
        const int i = tid >> 3, h = tid & 7;
        float s1 = 0.f, s2 = 0.f;
#pragma unroll
        for (int c = 0; c < 32; ++c) {
            const float v = xw[i][h * 32 + c];
            s1 += v * sasrc[h * 32 + c];
            s2 += v * sadst[h * 32 + c];
        }
        sals[i][h] = s1;
        sald[i][h] = s2;
    }
    __syncthreads();

    // softmax over incoming edges per (dst, head)
    if (tid < 128) {
        const int d = tid >> 3, h = tid & 7;
        const float S = sS[h];
        const float aldv = sald[d][h];
        float alf[16];
        float m = -1e30f;
#pragma unroll
        for (int s = 0; s < 16; ++s) {
            float a;
            if (s == d) {
                if constexpr (SELF_LOOP) a = lrelu02(sals[s][h] + aldv + ea_mean[0] * S);
                else a = -1e30f;
            } else {
                const int el = s * 15 + d - (d > s ? 1 : 0);
                a = lrelu02(sals[s][h] + aldv + ea[g * EPG + el] * S);
            }
            alf[s] = a;
            m = fmaxf(m, a);
        }
        float sum = 0.f;
#pragma unroll
        for (int s = 0; s < 16; ++s) { alf[s] = expf(alf[s] - m); sum += alf[s]; }
        const float r = 1.f / (sum + 1e-16f);
#pragma unroll
        for (int s = 0; s < 16; ++s) coef[h][s][d] = alf[s] * r;
    }
    __syncthreads();

    // aggregate + bias + relu
    {
        const int h = tid >> 5;
        const float b = bias[tid];
        for (int d = 0; d < 16; ++d) {
            float acc = 0.f;
#pragma unroll
            for (int s = 0; s < 16; ++s) acc += coef[h][s][d] * xw[s][tid];
            hout[(g * 16 + d) * 256 + tid] = fmaxf(acc + b, 0.f);
        }
    }
}

// ---------------- pooling + actor heads: block = one graph ------------------
__global__ __launch_bounds__(256) void heads_kernel(
    const float* __restrict__ Hbuf, const float* __restrict__ x,
    const float* __restrict__ fc1W, const float* __restrict__ fc1b,
    const float* __restrict__ fc2W, const float* __restrict__ fc2b,
    float* __restrict__ out)
{
    __shared__ float hsh[16][256];
    __shared__ float gem[256];
    __shared__ float lash[8][3];
    __shared__ float hidn[8][128];

    const int tid = threadIdx.x, g = blockIdx.x;
    for (int r = 0; r < 16; ++r) hsh[r][tid] = Hbuf[(g * 16 + r) * 256 + tid];
    if (tid < 24) { int a = tid / 3, j = tid % 3; lash[a][j] = x[(g * 16 + a) * 29 + 26 + j]; }
    __syncthreads();
    {
        float s = 0.f;
#pragma unroll
        for (int r = 0; r < 16; ++r) s += hsh[r][tid];
        gem[tid] = s * (1.f / 16.f);
    }
    __syncthreads();

    // fc1: comb = [aemb(256) | gemb(256) | la(3)], 8 agents x 128 outs
    {
        const int o = tid & 127;
        const int a0 = (tid >> 7) * 4;
        const float* wr = &fc1W[o * 515];
        float acc0 = fc1b[o], acc1 = acc0, acc2 = acc0, acc3 = acc0;
        for (int k = 0; k < 256; ++k) {
            const float w = wr[k];
            acc0 += w * hsh[a0 + 0][k];
            acc1 += w * hsh[a0 + 1][k];
            acc2 += w * hsh[a0 + 2][k];
            acc3 += w * hsh[a0 + 3][k];
        }
        float gacc = 0.f;
        for (int k = 0; k < 256; ++k) gacc += wr[256 + k] * gem[k];
#pragma unroll
        for (int j = 0; j < 3; ++j) {
            const float w = wr[512 + j];
            acc0 += w * lash[a0 + 0][j];
            acc1 += w * lash[a0 + 1][j];
            acc2 += w * lash[a0 + 2][j];
            acc3 += w * lash[a0 + 3][j];
        }
        acc0 += gacc; acc1 += gacc; acc2 += gacc; acc3 += gacc;
        hidn[a0 + 0][o] = fmaxf(acc0, 0.f);
        hidn[a0 + 1][o] = fmaxf(acc1, 0.f);
        hidn[a0 + 2][o] = fmaxf(acc2, 0.f);
        hidn[a0 + 3][o] = fmaxf(acc3, 0.f);
    }
    __syncthreads();

    // fc2 + output transforms
    if (tid < 48) {
        const int a = tid / 6, j = tid % 6;
        const float* wr = &fc2W[j * 128];
        float acc = fc2b[j];
#pragma unroll
        for (int k = 0; k < 128; ++k) acc += wr[k] * hidn[a][k];
        const int base = (g * 8 + a) * 3;
        if (j < 3) {
            const float lim = (j == 2) ? 3.1415927f : 1.0f;
            out[OUT_MEAN + base + j] = tanhf(acc) * lim;
        } else {
            const float sg = 1.f / (1.f + expf(-acc));
            out[OUT_STD + base + (j - 3)] = 0.01f + sg * (0.3f - 0.01f) + 1e-5f;
        }
    }
}

extern "C" void kernel_launch(void* const* d_in, const int* in_sizes, int n_in,
                              void* d_out, int out_size, void* d_ws, size_t ws_size,
                              hipStream_t stream)
{
    const float* x     = (const float*)d_in[0];
    const float* ea    = (const float*)d_in[2];
    const float* lc_w1 = (const float*)d_in[6];
    const float* lc_b1 = (const float*)d_in[7];
    const float* lc_w2 = (const float*)d_in[8];
    const float* lc_b2 = (const float*)d_in[9];
    const float* lc_wl = (const float*)d_in[10];
    const float* lc_bl = (const float*)d_in[11];
    const float* ld_w1 = (const float*)d_in[12];
    const float* ld_b1 = (const float*)d_in[13];
    const float* ld_w2 = (const float*)d_in[14];
    const float* ld_b2 = (const float*)d_in[15];
    const float* g1_W  = (const float*)d_in[16];
    const float* g1_as = (const float*)d_in[17];
    const float* g1_ad = (const float*)d_in[18];
    const float* g1_We = (const float*)d_in[19];
    const float* g1_ae = (const float*)d_in[20];
    const float* g1_b  = (const float*)d_in[21];
    const float* g2_W  = (const float*)d_in[22];
    const float* g2_as = (const float*)d_in[23];
    const float* g2_ad = (const float*)d_in[24];
    const float* g2_We = (const float*)d_in[25];
    const float* g2_ae = (const float*)d_in[26];
    const float* g2_b  = (const float*)d_in[27];
    const float* g3_W  = (const float*)d_in[28];
    const float* g3_as = (const float*)d_in[29];
    const float* g3_ad = (const float*)d_in[30];
    const float* g3_We = (const float*)d_in[31];
    const float* g3_ae = (const float*)d_in[32];
    const float* g3_b  = (const float*)d_in[33];
    const float* fc1_W = (const float*)d_in[34];
    const float* fc1_b = (const float*)d_in[35];
    const float* fc2_W = (const float*)d_in[36];
    const float* fc2_b = (const float*)d_in[37];

    float* out = (float*)d_out;
    float* HA = (float*)d_ws;                 // 16384*256 floats
    float* HB = HA + (size_t)NODES * FDIM;    // 16384*256 floats
    float* partial = HB + (size_t)NODES * FDIM;
    float* eamean = partial + 256;

    ea_partial_kernel<<<256, 256, 0, stream>>>(ea, partial);
    ea_final_kernel<<<1, 256, 0, stream>>>(partial, eamean);

    lidar_kernel<<<64, 256, 0, stream>>>(x, lc_w1, lc_b1, lc_w2, lc_b2, lc_wl, lc_bl,
                                         ld_w1, ld_b1, ld_w2, ld_b2, out);

    gat_kernel<6, false><<<NGRAPH, 256, 0, stream>>>(x, g1_W, g1_as, g1_ad, g1_We, g1_ae,
                                                     g1_b, ea, eamean, HA);
    gat_kernel<256, true><<<NGRAPH, 256, 0, stream>>>(HA, g2_W, g2_as, g2_ad, g2_We, g2_ae,
                                                      g2_b, ea, eamean, HB);
    gat_kernel<256, true><<<NGRAPH, 256, 0, stream>>>(HB, g3_W, g3_as, g3_ad, g3_We, g3_ae,
                                                      g3_b, ea, eamean, HA);

    heads_kernel<<<NGRAPH, 256, 0, stream>>>(HA, x, fc1_W, fc1_b, fc2_W, fc2_b, out);
}

// Round 2
// 263.778 us; speedup vs baseline: 1.1748x; 1.1748x over previous
//
#include <hip/hip_runtime.h>
#include <math.h>

#define NODES   16384
#define NGRAPH  1024
#define EDGES   245760
#define EPG     240
#define FDIM    256

#define OUT_MEAN  0
#define OUT_STD   24576
#define OUT_SCANS 49152
#define OUT_RECON 376832

static __device__ __forceinline__ float lrelu02(float v){ return v > 0.f ? v : 0.2f*v; }

// ---------------- edge_attr mean (two-stage deterministic reduction) --------
__global__ __launch_bounds__(256) void ea_partial_kernel(const float* __restrict__ ea,
                                                         float* __restrict__ partial)
{
    __shared__ float red[256];
    const int tid = threadIdx.x;
    const int base = blockIdx.x * 960;   // 256 blocks * 960 = 245760
    float s = 0.f;
    for (int i = tid; i < 960; i += 256) s += ea[base + i];
    red[tid] = s; __syncthreads();
    for (int off = 128; off > 0; off >>= 1) {
        if (tid < off) red[tid] += red[tid + off];
        __syncthreads();
    }
    if (tid == 0) partial[blockIdx.x] = red[0];
}

__global__ __launch_bounds__(256) void ea_final_kernel(const float* __restrict__ partial,
                                                       float* __restrict__ mean_out)
{
    __shared__ float red[256];
    const int tid = threadIdx.x;
    red[tid] = partial[tid]; __syncthreads();
    for (int off = 128; off > 0; off >>= 1) {
        if (tid < off) red[tid] += red[tid + off];
        __syncthreads();
    }
    if (tid == 0) mean_out[0] = red[0] * (1.f / (float)EDGES);
}

// ---------------- lidar encoder + recon (4 threads per node) ----------------
// Thread tsub in [0,4) of node n handles conv2 output positions t = tsub,
// tsub+4, tsub+8 (<10), recomputing the 3 pooled conv1 columns each needs.
// The 32 pooled-mean channels are then reduced across the 4 lanes with a
// shuffle butterfly; the tiny FC/decoder tail is computed redundantly and
// each lane writes 5 of the 20 recon outputs.
__global__ __launch_bounds__(256) void lidar_kernel(
    const float* __restrict__ x,
    const float* __restrict__ w1, const float* __restrict__ b1,
    const float* __restrict__ w2, const float* __restrict__ b2,
    const float* __restrict__ wl, const float* __restrict__ bl,
    const float* __restrict__ dw1, const float* __restrict__ db1,
    const float* __restrict__ dw2, const float* __restrict__ db2,
    float* __restrict__ out)
{
    __shared__ float sc[64][25];   // padded scans: [0..1]=0, [2..21]=scan, [22..24]=0
    const int tid  = threadIdx.x;
    const int tsub = tid & 3;
    const int nl   = tid >> 2;                 // local node 0..63
    const int n    = blockIdx.x * 64 + nl;

    // stage scans (each thread loads 5) + emit scans output copy
    if (tsub == 0) { sc[nl][0] = 0.f; sc[nl][1] = 0.f; }
    if (tsub == 3) { sc[nl][22] = 0.f; sc[nl][23] = 0.f; sc[nl][24] = 0.f; }
#pragma unroll
    for (int j = 0; j < 5; ++j) {
        const int t = tsub * 5 + j;
        const float v = x[n * 29 + t];
        sc[nl][t + 2] = v;
        out[OUT_SCANS + n * 20 + t] = v;
    }
    __syncthreads();

    float macc[32];
#pragma unroll
    for (int oc = 0; oc < 32; ++oc) macc[oc] = 0.f;

    // positions handled by this lane
    for (int t = tsub; t < 10; t += 4) {
        float pc[3][16];   // pooled columns t-1, t, t+1
#pragma unroll
        for (int j = 0; j < 3; ++j) {
            const int u = t - 1 + j;
            if (u < 0 || u > 9) {
#pragma unroll
                for (int ic = 0; ic < 16; ++ic) pc[j][ic] = 0.f;
            } else {
                const int p0 = 2 * u;   // conv1 positions p0, p0+1; sc idx = p + k
#pragma unroll
                for (int ic = 0; ic < 16; ++ic) {
                    float a = b1[ic], b = b1[ic];
#pragma unroll
                    for (int k = 0; k < 5; ++k) {
                        const float w = w1[ic * 5 + k];
                        a += sc[nl][p0 + k] * w;
                        b += sc[nl][p0 + 1 + k] * w;
                    }
                    pc[j][ic] = fmaxf(fmaxf(a, b), 0.f);
                }
            }
        }
#pragma unroll
        for (int oc = 0; oc < 32; ++oc) {
            float v = b2[oc];
            const float* wrow = &w2[oc * 48];
#pragma unroll
            for (int ic = 0; ic < 16; ++ic) {
                v += pc[0][ic] * wrow[ic * 3 + 0]
                   + pc[1][ic] * wrow[ic * 3 + 1]
                   + pc[2][ic] * wrow[ic * 3 + 2];
            }
            macc[oc] += fmaxf(v, 0.f);
        }
    }

    // reduce macc over the 4 lanes of this node (butterfly -> all lanes hold sum)
#pragma unroll
    for (int oc = 0; oc < 32; ++oc) {
        float v = macc[oc];
        v += __shfl_xor(v, 1);
        v += __shfl_xor(v, 2);
        macc[oc] = v;
    }

    // z = relu(feat @ wl.T + bl), feat = macc/10   (redundant on 4 lanes)
    float z[5];
#pragma unroll
    for (int j = 0; j < 5; ++j) {
        float v = bl[j];
#pragma unroll
        for (int c = 0; c < 32; ++c) v += (macc[c] * 0.1f) * wl[j * 32 + c];
        z[j] = fmaxf(v, 0.f);
    }
    float hid[32];
#pragma unroll
    for (int k = 0; k < 32; ++k) {
        float v = db1[k];
#pragma unroll
        for (int j = 0; j < 5; ++j) v += z[j] * dw1[k * 5 + j];
        hid[k] = fmaxf(v, 0.f);
    }
    // recon: each lane writes 5 of 20 outputs
#pragma unroll
    for (int j = 0; j < 5; ++j) {
        const int t = tsub * 5 + j;
        float v = db2[t];
#pragma unroll
        for (int k = 0; k < 32; ++k) v += hid[k] * dw2[t * 32 + k];
        out[OUT_RECON + n * 20 + t] = v;
    }
}

// ---------------- fused GAT layer: block = one graph (16 nodes) -------------
template <int IN_K, bool SELF_LOOP>
__global__ __launch_bounds__(256) void gat_kernel(
    const float* __restrict__ hin,
    const float* __restrict__ W,       // (IN_K, 256)
    const float* __restrict__ asrc,    // (8,32)
    const float* __restrict__ adst,    // (8,32)
    const float* __restrict__ We,      // (256)
    const float* __restrict__ ae,      // (8,32)
    const float* __restrict__ bias,    // (256)
    const float* __restrict__ ea,      // (EDGES)
    const float* __restrict__ ea_mean, // 1 float
    float* __restrict__ hout)
{
    __shared__ float hs[16][IN_K];
    __shared__ float xw[16][256];
    __shared__ float coef[8][16][16];   // [h][s][d]
    __shared__ float sals[16][8], sald[16][8];
    __shared__ float sasrc[256], sadst[256], sS[8];

    const int tid = threadIdx.x;
    const int g = blockIdx.x;

    if constexpr (IN_K == 6) {
        if (tid < 96) { int i = tid / 6, k = tid % 6; hs[i][k] = hin[(g * 16 + i) * 29 + 20 + k]; }
    } else {
        for (int r = 0; r < 16; ++r) hs[r][tid] = hin[(g * 16 + r) * 256 + tid];
    }
    sasrc[tid] = asrc[tid];
    sadst[tid] = adst[tid];
    if (tid < 8) {
        float s = 0.f;
        for (int c = 0; c < 32; ++c) s += We[tid * 32 + c] * ae[tid * 32 + c];
        sS[tid] = s;
    }
    __syncthreads();

    // GEMM: xw[i][tid] = sum_k hs[i][k] * W[k][tid]
    {
        float acc[16];
#pragma unroll
        for (int i = 0; i < 16; ++i) acc[i] = 0.f;
        if constexpr (IN_K == 6) {
#pragma unroll
            for (int k = 0; k < 6; ++k) {
                float w = W[k * 256 + tid];
#pragma unroll
                for (int i = 0; i < 16; ++i) acc[i] += hs[i][k] * w;
            }
        } else {
            for (int k0 = 0; k0 < 256; k0 += 4) {
                const float w0 = W[(k0 + 0) * 256 + tid];
                const float w1v = W[(k0 + 1) * 256 + tid];
                const float w2v = W[(k0 + 2) * 256 + tid];
                const float w3v = W[(k0 + 3) * 256 + tid];
#pragma unroll
                for (int i = 0; i < 16; ++i) {
                    const float4 h4 = *reinterpret_cast<const float4*>(&hs[i][k0]);
                    acc[i] += h4.x * w0 + h4.y * w1v + h4.z * w2v + h4.w * w3v;
                }
            }
        }
#pragma unroll
        for (int i = 0; i < 16; ++i) xw[i][tid] = acc[i];
    }
    __syncthreads();

    // als/ald per (node, head)
    if (tid < 128) {
        const int i = tid >> 3, h = tid & 7;
        float s1 = 0.f, s2 = 0.f;
#pragma unroll
        for (int c = 0; c < 32; ++c) {
            const float v = xw[i][h * 32 + c];
            s1 += v * sasrc[h * 32 + c];
            s2 += v * sadst[h * 32 + c];
        }
        sals[i][h] = s1;
        sald[i][h] = s2;
    }
    __syncthreads();

    // softmax over incoming edges per (dst, head)
    if (tid < 128) {
        const int d = tid >> 3, h = tid & 7;
        const float S = sS[h];
        const float aldv = sald[d][h];
        float alf[16];
        float m = -1e30f;
#pragma unroll
        for (int s = 0; s < 16; ++s) {
            float a;
            if (s == d) {
                if constexpr (SELF_LOOP) a = lrelu02(sals[s][h] + aldv + ea_mean[0] * S);
                else a = -1e30f;
            } else {
                const int el = s * 15 + d - (d > s ? 1 : 0);
                a = lrelu02(sals[s][h] + aldv + ea[g * EPG + el] * S);
            }
            alf[s] = a;
            m = fmaxf(m, a);
        }
        float sum = 0.f;
#pragma unroll
        for (int s = 0; s < 16; ++s) { alf[s] = expf(alf[s] - m); sum += alf[s]; }
        const float r = 1.f / (sum + 1e-16f);
#pragma unroll
        for (int s = 0; s < 16; ++s) coef[h][s][d] = alf[s] * r;
    }
    __syncthreads();

    // aggregate + bias + relu
    {
        const int h = tid >> 5;
        const float b = bias[tid];
        for (int d = 0; d < 16; ++d) {
            float acc = 0.f;
#pragma unroll
            for (int s = 0; s < 16; ++s) acc += coef[h][s][d] * xw[s][tid];
            hout[(g * 16 + d) * 256 + tid] = fmaxf(acc + b, 0.f);
        }
    }
}

// ---------------- pooling + actor heads: block = one graph ------------------
__global__ __launch_bounds__(256) void heads_kernel(
    const float* __restrict__ Hbuf, const float* __restrict__ x,
    const float* __restrict__ fc1W, const float* __restrict__ fc1b,
    const float* __restrict__ fc2W, const float* __restrict__ fc2b,
    float* __restrict__ out)
{
    __shared__ float hsh[16][256];
    __shared__ float gem[256];
    __shared__ float lash[8][3];
    __shared__ float hidn[8][128];

    const int tid = threadIdx.x, g = blockIdx.x;
    for (int r = 0; r < 16; ++r) hsh[r][tid] = Hbuf[(g * 16 + r) * 256 + tid];
    if (tid < 24) { int a = tid / 3, j = tid % 3; lash[a][j] = x[(g * 16 + a) * 29 + 26 + j]; }
    __syncthreads();
    {
        float s = 0.f;
#pragma unroll
        for (int r = 0; r < 16; ++r) s += hsh[r][tid];
        gem[tid] = s * (1.f / 16.f);
    }
    __syncthreads();

    // fc1: comb = [aemb(256) | gemb(256) | la(3)], 8 agents x 128 outs
    {
        const int o = tid & 127;
        const int a0 = (tid >> 7) * 4;
        const float* wr = &fc1W[o * 515];
        float acc0 = fc1b[o], acc1 = acc0, acc2 = acc0, acc3 = acc0;
        for (int k = 0; k < 256; ++k) {
            const float w = wr[k];
            acc0 += w * hsh[a0 + 0][k];
            acc1 += w * hsh[a0 + 1][k];
            acc2 += w * hsh[a0 + 2][k];
            acc3 += w * hsh[a0 + 3][k];
        }
        float gacc = 0.f;
        for (int k = 0; k < 256; ++k) gacc += wr[256 + k] * gem[k];
#pragma unroll
        for (int j = 0; j < 3; ++j) {
            const float w = wr[512 + j];
            acc0 += w * lash[a0 + 0][j];
            acc1 += w * lash[a0 + 1][j];
            acc2 += w * lash[a0 + 2][j];
            acc3 += w * lash[a0 + 3][j];
        }
        acc0 += gacc; acc1 += gacc; acc2 += gacc; acc3 += gacc;
        hidn[a0 + 0][o] = fmaxf(acc0, 0.f);
        hidn[a0 + 1][o] = fmaxf(acc1, 0.f);
        hidn[a0 + 2][o] = fmaxf(acc2, 0.f);
        hidn[a0 + 3][o] = fmaxf(acc3, 0.f);
    }
    __syncthreads();

    // fc2 + output transforms
    if (tid < 48) {
        const int a = tid / 6, j = tid % 6;
        const float* wr = &fc2W[j * 128];
        float acc = fc2b[j];
#pragma unroll
        for (int k = 0; k < 128; ++k) acc += wr[k] * hidn[a][k];
        const int base = (g * 8 + a) * 3;
        if (j < 3) {
            const float lim = (j == 2) ? 3.1415927f : 1.0f;
            out[OUT_MEAN + base + j] = tanhf(acc) * lim;
        } else {
            const float sg = 1.f / (1.f + expf(-acc));
            out[OUT_STD + base + (j - 3)] = 0.01f + sg * (0.3f - 0.01f) + 1e-5f;
        }
    }
}

extern "C" void kernel_launch(void* const* d_in, const int* in_sizes, int n_in,
                              void* d_out, int out_size, void* d_ws, size_t ws_size,
                              hipStream_t stream)
{
    const float* x     = (const float*)d_in[0];
    const float* ea    = (const float*)d_in[2];
    const float* lc_w1 = (const float*)d_in[6];
    const float* lc_b1 = (const float*)d_in[7];
    const float* lc_w2 = (const float*)d_in[8];
    const float* lc_b2 = (const float*)d_in[9];
    const float* lc_wl = (const float*)d_in[10];
    const float* lc_bl = (const float*)d_in[11];
    const float* ld_w1 = (const float*)d_in[12];
    const float* ld_b1 = (const float*)d_in[13];
    const float* ld_w2 = (const float*)d_in[14];
    const float* ld_b2 = (const float*)d_in[15];
    const float* g1_W  = (const float*)d_in[16];
    const float* g1_as = (const float*)d_in[17];
    const float* g1_ad = (const float*)d_in[18];
    const float* g1_We = (const float*)d_in[19];
    const float* g1_ae = (const float*)d_in[20];
    const float* g1_b  = (const float*)d_in[21];
    const float* g2_W  = (const float*)d_in[22];
    const float* g2_as = (const float*)d_in[23];
    const float* g2_ad = (const float*)d_in[24];
    const float* g2_We = (const float*)d_in[25];
    const float* g2_ae = (const float*)d_in[26];
    const float* g2_b  = (const float*)d_in[27];
    const float* g3_W  = (const float*)d_in[28];
    const float* g3_as = (const float*)d_in[29];
    const float* g3_ad = (const float*)d_in[30];
    const float* g3_We = (const float*)d_in[31];
    const float* g3_ae = (const float*)d_in[32];
    const float* g3_b  = (const float*)d_in[33];
    const float* fc1_W = (const float*)d_in[34];
    const float* fc1_b = (const float*)d_in[35];
    const float* fc2_W = (const float*)d_in[36];
    const float* fc2_b = (const float*)d_in[37];

    float* out = (float*)d_out;
    float* HA = (float*)d_ws;                 // 16384*256 floats
    float* HB = HA + (size_t)NODES * FDIM;    // 16384*256 floats
    float* partial = HB + (size_t)NODES * FDIM;
    float* eamean = partial + 256;

    ea_partial_kernel<<<256, 256, 0, stream>>>(ea, partial);
    ea_final_kernel<<<1, 256, 0, stream>>>(partial, eamean);

    lidar_kernel<<<256, 256, 0, stream>>>(x, lc_w1, lc_b1, lc_w2, lc_b2, lc_wl, lc_bl,
                                          ld_w1, ld_b1, ld_w2, ld_b2, out);

    gat_kernel<6, false><<<NGRAPH, 256, 0, stream>>>(x, g1_W, g1_as, g1_ad, g1_We, g1_ae,
                                                     g1_b, ea, eamean, HA);
    gat_kernel<256, true><<<NGRAPH, 256, 0, stream>>>(HA, g2_W, g2_as, g2_ad, g2_We, g2_ae,
                                                      g2_b, ea, eamean, HB);
    gat_kernel<256, true><<<NGRAPH, 256, 0, stream>>>(HB, g3_W, g3_as, g3_ad, g3_We, g3_ae,
                                                      g3_b, ea, eamean, HA);

    heads_kernel<<<NGRAPH, 256, 0, stream>>>(HA, x, fc1_W, fc1_b, fc2_W, fc2_b, out);
}

// Round 4
// 206.351 us; speedup vs baseline: 1.5017x; 1.2783x over previous
//
#include <hip/hip_runtime.h>
#include <math.h>

#define NODES   16384
#define NGRAPH  1024
#define EDGES   245760
#define EPG     240
#define FDIM    256

#define OUT_MEAN  0
#define OUT_STD   24576
#define OUT_SCANS 49152
#define OUT_RECON 376832

typedef __attribute__((ext_vector_type(4))) short bf16x4;
typedef __attribute__((ext_vector_type(8))) short bf16x8;
typedef __attribute__((ext_vector_type(4))) float f32x4;

static __device__ __forceinline__ float lrelu02(float v){ return v > 0.f ? v : 0.2f*v; }

static __device__ __forceinline__ unsigned short f2bf(float f){
    unsigned u = __float_as_uint(f);
    u = (u + 0x7FFFu + ((u >> 16) & 1u)) >> 16;
    return (unsigned short)u;
}
static __device__ __forceinline__ float bf2f(unsigned short h){
    return __uint_as_float(((unsigned)h) << 16);
}

// ---------------- edge_attr mean (two-stage deterministic reduction) --------
__global__ __launch_bounds__(256) void ea_partial_kernel(const float* __restrict__ ea,
                                                         float* __restrict__ partial)
{
    __shared__ float red[256];
    const int tid = threadIdx.x;
    const int base = blockIdx.x * 960;
    float s = 0.f;
    for (int i = tid; i < 960; i += 256) s += ea[base + i];
    red[tid] = s; __syncthreads();
    for (int off = 128; off > 0; off >>= 1) {
        if (tid < off) red[tid] += red[tid + off];
        __syncthreads();
    }
    if (tid == 0) partial[blockIdx.x] = red[0];
}

__global__ __launch_bounds__(256) void ea_final_kernel(const float* __restrict__ partial,
                                                       float* __restrict__ mean_out)
{
    __shared__ float red[256];
    const int tid = threadIdx.x;
    red[tid] = partial[tid]; __syncthreads();
    for (int off = 128; off > 0; off >>= 1) {
        if (tid < off) red[tid] += red[tid + off];
        __syncthreads();
    }
    if (tid == 0) mean_out[0] = red[0] * (1.f / (float)EDGES);
}

// ---------------- W transpose + bf16 convert: WT[n][k] = bf16(W[k][n]) ------
__global__ __launch_bounds__(256) void wtrans_kernel(
    const float* __restrict__ W2, const float* __restrict__ W3,
    unsigned short* __restrict__ T2, unsigned short* __restrict__ T3)
{
    const int b = blockIdx.x;
    const float* W = (b < 256) ? W2 : W3;
    unsigned short* T = (b < 256) ? T2 : T3;
    const int n = b & 255, k = threadIdx.x;
    T[n * 256 + k] = f2bf(W[k * 256 + n]);
}

// ---------------- lidar encoder + recon (4 threads per node) ----------------
__global__ __launch_bounds__(256) void lidar_kernel(
    const float* __restrict__ x,
    const float* __restrict__ w1, const float* __restrict__ b1,
    const float* __restrict__ w2, const float* __restrict__ b2,
    const float* __restrict__ wl, const float* __restrict__ bl,
    const float* __restrict__ dw1, const float* __restrict__ db1,
    const float* __restrict__ dw2, const float* __restrict__ db2,
    float* __restrict__ out)
{
    __shared__ float sc[64][25];
    const int tid  = threadIdx.x;
    const int tsub = tid & 3;
    const int nl   = tid >> 2;
    const int n    = blockIdx.x * 64 + nl;

    if (tsub == 0) { sc[nl][0] = 0.f; sc[nl][1] = 0.f; }
    if (tsub == 3) { sc[nl][22] = 0.f; sc[nl][23] = 0.f; sc[nl][24] = 0.f; }
#pragma unroll
    for (int j = 0; j < 5; ++j) {
        const int t = tsub * 5 + j;
        const float v = x[n * 29 + t];
        sc[nl][t + 2] = v;
        out[OUT_SCANS + n * 20 + t] = v;
    }
    __syncthreads();

    float macc[32];
#pragma unroll
    for (int oc = 0; oc < 32; ++oc) macc[oc] = 0.f;

    for (int t = tsub; t < 10; t += 4) {
        float pc[3][16];
#pragma unroll
        for (int j = 0; j < 3; ++j) {
            const int u = t - 1 + j;
            if (u < 0 || u > 9) {
#pragma unroll
                for (int ic = 0; ic < 16; ++ic) pc[j][ic] = 0.f;
            } else {
                const int p0 = 2 * u;
#pragma unroll
                for (int ic = 0; ic < 16; ++ic) {
                    float a = b1[ic], b = b1[ic];
#pragma unroll
                    for (int k = 0; k < 5; ++k) {
                        const float w = w1[ic * 5 + k];
                        a += sc[nl][p0 + k] * w;
                        b += sc[nl][p0 + 1 + k] * w;
                    }
                    pc[j][ic] = fmaxf(fmaxf(a, b), 0.f);
                }
            }
        }
#pragma unroll
        for (int oc = 0; oc < 32; ++oc) {
            float v = b2[oc];
            const float* wrow = &w2[oc * 48];
#pragma unroll
            for (int ic = 0; ic < 16; ++ic) {
                v += pc[0][ic] * wrow[ic * 3 + 0]
                   + pc[1][ic] * wrow[ic * 3 + 1]
                   + pc[2][ic] * wrow[ic * 3 + 2];
            }
            macc[oc] += fmaxf(v, 0.f);
        }
    }

#pragma unroll
    for (int oc = 0; oc < 32; ++oc) {
        float v = macc[oc];
        v += __shfl_xor(v, 1);
        v += __shfl_xor(v, 2);
        macc[oc] = v;
    }

    float z[5];
#pragma unroll
    for (int j = 0; j < 5; ++j) {
        float v = bl[j];
#pragma unroll
        for (int c = 0; c < 32; ++c) v += (macc[c] * 0.1f) * wl[j * 32 + c];
        z[j] = fmaxf(v, 0.f);
    }
    float hid[32];
#pragma unroll
    for (int k = 0; k < 32; ++k) {
        float v = db1[k];
#pragma unroll
        for (int j = 0; j < 5; ++j) v += z[j] * dw1[k * 5 + j];
        hid[k] = fmaxf(v, 0.f);
    }
#pragma unroll
    for (int j = 0; j < 5; ++j) {
        const int t = tsub * 5 + j;
        float v = db2[t];
#pragma unroll
        for (int k = 0; k < 32; ++k) v += hid[k] * dw2[t * 32 + k];
        out[OUT_RECON + n * 20 + t] = v;
    }
}

// ---------------- GAT layer 1 (K=6, VALU path, no self loops, bf16 out) -----
__global__ __launch_bounds__(256) void gat1_kernel(
    const float* __restrict__ hin,
    const float* __restrict__ W,       // (6, 256)
    const float* __restrict__ asrc, const float* __restrict__ adst,
    const float* __restrict__ We,  const float* __restrict__ ae,
    const float* __restrict__ bias,
    const float* __restrict__ ea,
    unsigned short* __restrict__ hout16)
{
    __shared__ float hs[16][6];
    __shared__ float xw[16][256];
    __shared__ float coef[16][16][8];   // [s][d][h]
    __shared__ float sals[16][8], sald[16][8];
    __shared__ float sasrc[256], sadst[256], sS[8];

    const int tid = threadIdx.x, g = blockIdx.x;

    if (tid < 96) { int i = tid / 6, k = tid % 6; hs[i][k] = hin[(g * 16 + i) * 29 + 20 + k]; }
    sasrc[tid] = asrc[tid];
    sadst[tid] = adst[tid];
    if (tid < 8) {
        float s = 0.f;
        for (int c = 0; c < 32; ++c) s += We[tid * 32 + c] * ae[tid * 32 + c];
        sS[tid] = s;
    }
    __syncthreads();

    {
        float acc[16];
#pragma unroll
        for (int i = 0; i < 16; ++i) acc[i] = 0.f;
#pragma unroll
        for (int k = 0; k < 6; ++k) {
            float w = W[k * 256 + tid];
#pragma unroll
            for (int i = 0; i < 16; ++i) acc[i] += hs[i][k] * w;
        }
#pragma unroll
        for (int i = 0; i < 16; ++i) xw[i][tid] = acc[i];
    }
    __syncthreads();

    if (tid < 128) {
        const int i = tid >> 3, h = tid & 7;
        float s1 = 0.f, s2 = 0.f;
#pragma unroll
        for (int c0 = 0; c0 < 32; c0 += 4) {
            const float4 v  = *(const float4*)&xw[i][h * 32 + c0];
            const float4 a1 = *(const float4*)&sasrc[h * 32 + c0];
            const float4 a2 = *(const float4*)&sadst[h * 32 + c0];
            s1 += v.x * a1.x + v.y * a1.y + v.z * a1.z + v.w * a1.w;
            s2 += v.x * a2.x + v.y * a2.y + v.z * a2.z + v.w * a2.w;
        }
        sals[i][h] = s1;
        sald[i][h] = s2;
    }
    __syncthreads();

    if (tid < 128) {
        const int d = tid >> 3, h = tid & 7;
        const float S = sS[h];
        const float aldv = sald[d][h];
        float alf[16];
        float m = -1e30f;
#pragma unroll
        for (int s = 0; s < 16; ++s) {
            float a;
            if (s == d) a = -1e30f;
            else {
                const int el = s * 15 + d - (d > s ? 1 : 0);
                a = lrelu02(sals[s][h] + aldv + ea[g * EPG + el] * S);
            }
            alf[s] = a;
            m = fmaxf(m, a);
        }
        float sum = 0.f;
#pragma unroll
        for (int s = 0; s < 16; ++s) { alf[s] = expf(alf[s] - m); sum += alf[s]; }
        const float r = 1.f / (sum + 1e-16f);
#pragma unroll
        for (int s = 0; s < 16; ++s) coef[s][d][h] = alf[s] * r;
    }
    __syncthreads();

    {
        const int h = tid >> 5;
        const float b = bias[tid];
        float o[16];
#pragma unroll
        for (int d = 0; d < 16; ++d) o[d] = b;
        for (int s = 0; s < 16; ++s) {
            const float xv = xw[s][tid];
#pragma unroll
            for (int d = 0; d < 16; ++d) o[d] += coef[s][d][h] * xv;
        }
        unsigned short* dst = hout16 + (size_t)g * 16 * 256 + tid;
#pragma unroll
        for (int d = 0; d < 16; ++d) dst[d * 256] = f2bf(fmaxf(o[d], 0.f));
    }
}

// ---------------- GAT layers 2/3: MFMA GEMM + fused attention ---------------
// Block = one graph (16 nodes), 4 waves. Wave w computes xw[:, w*64..w*64+64)
// via mfma_f32_16x16x32_bf16. Fragment maps (two stacked K=16 halves):
//   A: row = lane&15, k = kk*32 + (lane>>4)*4 + (j&3) + 16*(j>>2)
//   B: col = lane&15, same k map   (B read from WT[n][k] = W[k][n])
//   D: col = lane&15, row = (lane>>4)*4 + r
__global__ __launch_bounds__(256) void gat_mfma_kernel(
    const unsigned short* __restrict__ hin16,  // [N][256] bf16
    const unsigned short* __restrict__ WT16,   // [256][256] bf16, WT[n][k]
    const float* __restrict__ asrc, const float* __restrict__ adst,
    const float* __restrict__ We,  const float* __restrict__ ae,
    const float* __restrict__ bias,
    const float* __restrict__ ea,  const float* __restrict__ ea_mean,
    unsigned short* __restrict__ hout16)
{
    __shared__ char  hsb[8192];            // bf16 h tile [16][256], row-XOR swizzled
    __shared__ float xw[16][256];
    __shared__ float coef[16][16][8];      // [s][d][h]
    __shared__ float sals[16][8], sald[16][8];
    __shared__ float sasrc[256], sadst[256], sS[8];

    const int tid = threadIdx.x, g = blockIdx.x;
    const int lane = tid & 63, w = tid >> 6;

    // stage h tile (8KB contiguous in global) with row-XOR swizzle
    {
        const char* src = (const char*)(hin16 + (size_t)g * 16 * 256);
        const int c0 = tid * 2;
#pragma unroll
        for (int c = c0; c < c0 + 2; ++c) {
            const int row = c >> 5;
            const int kb  = (c & 31) << 4;
            const float4 v = *(const float4*)(src + row * 512 + kb);
            *(float4*)(hsb + ((row * 512 + kb) ^ ((row & 7) << 4))) = v;
        }
    }
    sasrc[tid] = asrc[tid];
    sadst[tid] = adst[tid];
    if (tid < 8) {
        float s = 0.f;
        for (int c = 0; c < 32; ++c) s += We[tid * 32 + c] * ae[tid * 32 + c];
        sS[tid] = s;
    }
    __syncthreads();

    // MFMA GEMM: xw = h @ W
    {
        f32x4 acc[4];
#pragma unroll
        for (int nt = 0; nt < 4; ++nt) acc[nt] = (f32x4){0.f, 0.f, 0.f, 0.f};
        const int arow = lane & 15;
        const int kg   = lane >> 4;
        const int aswz = (arow & 7) << 4;
        const char* wt = (const char*)WT16;
        for (int kk = 0; kk < 8; ++kk) {
            const int ab = arow * 512 + kk * 64 + kg * 8;
            const bf16x4 alo = *(const bf16x4*)(hsb + (ab ^ aswz));
            const bf16x4 ahi = *(const bf16x4*)(hsb + ((ab + 32) ^ aswz));
            const bf16x8 afrag = (bf16x8){alo[0], alo[1], alo[2], alo[3],
                                          ahi[0], ahi[1], ahi[2], ahi[3]};
#pragma unroll
            for (int nt = 0; nt < 4; ++nt) {
                const int ncol = w * 64 + nt * 16 + arow;
                const char* bp = wt + ncol * 512 + kk * 64 + kg * 8;
                const bf16x4 blo = *(const bf16x4*)(bp);
                const bf16x4 bhi = *(const bf16x4*)(bp + 32);
                const bf16x8 bfrag = (bf16x8){blo[0], blo[1], blo[2], blo[3],
                                              bhi[0], bhi[1], bhi[2], bhi[3]};
                acc[nt] = __builtin_amdgcn_mfma_f32_16x16x32_bf16(afrag, bfrag, acc[nt], 0, 0, 0);
            }
        }
#pragma unroll
        for (int nt = 0; nt < 4; ++nt) {
            const int col = w * 64 + nt * 16 + (lane & 15);
            const int r0  = (lane >> 4) * 4;
#pragma unroll
            for (int r = 0; r < 4; ++r) xw[r0 + r][col] = acc[nt][r];
        }
    }
    __syncthreads();

    if (tid < 128) {
        const int i = tid >> 3, h = tid & 7;
        float s1 = 0.f, s2 = 0.f;
#pragma unroll
        for (int c0 = 0; c0 < 32; c0 += 4) {
            const float4 v  = *(const float4*)&xw[i][h * 32 + c0];
            const float4 a1 = *(const float4*)&sasrc[h * 32 + c0];
            const float4 a2 = *(const float4*)&sadst[h * 32 + c0];
            s1 += v.x * a1.x + v.y * a1.y + v.z * a1.z + v.w * a1.w;
            s2 += v.x * a2.x + v.y * a2.y + v.z * a2.z + v.w * a2.w;
        }
        sals[i][h] = s1;
        sald[i][h] = s2;
    }
    __syncthreads();

    if (tid < 128) {
        const int d = tid >> 3, h = tid & 7;
        const float S = sS[h];
        const float aldv = sald[d][h];
        float alf[16];
        float m = -1e30f;
#pragma unroll
        for (int s = 0; s < 16; ++s) {
            float a;
            if (s == d) a = lrelu02(sals[s][h] + aldv + ea_mean[0] * S);
            else {
                const int el = s * 15 + d - (d > s ? 1 : 0);
                a = lrelu02(sals[s][h] + aldv + ea[g * EPG + el] * S);
            }
            alf[s] = a;
            m = fmaxf(m, a);
        }
        float sum = 0.f;
#pragma unroll
        for (int s = 0; s < 16; ++s) { alf[s] = expf(alf[s] - m); sum += alf[s]; }
        const float r = 1.f / (sum + 1e-16f);
#pragma unroll
        for (int s = 0; s < 16; ++s) coef[s][d][h] = alf[s] * r;
    }
    __syncthreads();

    {
        const int h = tid >> 5;
        const float b = bias[tid];
        float o[16];
#pragma unroll
        for (int d = 0; d < 16; ++d) o[d] = b;
        for (int s = 0; s < 16; ++s) {
            const float xv = xw[s][tid];
#pragma unroll
            for (int d = 0; d < 16; ++d) o[d] += coef[s][d][h] * xv;
        }
        unsigned short* dst = hout16 + (size_t)g * 16 * 256 + tid;
#pragma unroll
        for (int d = 0; d < 16; ++d) dst[d * 256] = f2bf(fmaxf(o[d], 0.f));
    }
}

// ---------------- pooling + actor heads (bf16 h input) ----------------------
__global__ __launch_bounds__(256) void heads_kernel(
    const unsigned short* __restrict__ Hb, const float* __restrict__ x,
    const float* __restrict__ fc1W, const float* __restrict__ fc1b,
    const float* __restrict__ fc2W, const float* __restrict__ fc2b,
    float* __restrict__ out)
{
    __shared__ float hsh[16][256];
    __shared__ float gem[256];
    __shared__ float lash[8][3];
    __shared__ float hidn[8][128];

    const int tid = threadIdx.x, g = blockIdx.x;
    for (int r = 0; r < 16; ++r) hsh[r][tid] = bf2f(Hb[(size_t)(g * 16 + r) * 256 + tid]);
    if (tid < 24) { int a = tid / 3, j = tid % 3; lash[a][j] = x[(g * 16 + a) * 29 + 26 + j]; }
    __syncthreads();
    {
        float s = 0.f;
#pragma unroll
        for (int r = 0; r < 16; ++r) s += hsh[r][tid];
        gem[tid] = s * (1.f / 16.f);
    }
    __syncthreads();

    {
        const int o = tid & 127;
        const int a0 = (tid >> 7) * 4;
        const float* wr = &fc1W[o * 515];
        float acc0 = fc1b[o], acc1 = acc0, acc2 = acc0, acc3 = acc0;
        for (int k = 0; k < 256; ++k) {
            const float w = wr[k];
            acc0 += w * hsh[a0 + 0][k];
            acc1 += w * hsh[a0 + 1][k];
            acc2 += w * hsh[a0 + 2][k];
            acc3 += w * hsh[a0 + 3][k];
        }
        float gacc = 0.f;
        for (int k = 0; k < 256; ++k) gacc += wr[256 + k] * gem[k];
#pragma unroll
        for (int j = 0; j < 3; ++j) {
            const float w = wr[512 + j];
            acc0 += w * lash[a0 + 0][j];
            acc1 += w * lash[a0 + 1][j];
            acc2 += w * lash[a0 + 2][j];
            acc3 += w * lash[a0 + 3][j];
        }
        acc0 += gacc; acc1 += gacc; acc2 += gacc; acc3 += gacc;
        hidn[a0 + 0][o] = fmaxf(acc0, 0.f);
        hidn[a0 + 1][o] = fmaxf(acc1, 0.f);
        hidn[a0 + 2][o] = fmaxf(acc2, 0.f);
        hidn[a0 + 3][o] = fmaxf(acc3, 0.f);
    }
    __syncthreads();

    if (tid < 48) {
        const int a = tid / 6, j = tid % 6;
        const float* wr = &fc2W[j * 128];
        float acc = fc2b[j];
#pragma unroll
        for (int k = 0; k < 128; ++k) acc += wr[k] * hidn[a][k];
        const int base = (g * 8 + a) * 3;
        if (j < 3) {
            const float lim = (j == 2) ? 3.1415927f : 1.0f;
            out[OUT_MEAN + base + j] = tanhf(acc) * lim;
        } else {
            const float sg = 1.f / (1.f + expf(-acc));
            out[OUT_STD + base + (j - 3)] = 0.01f + sg * (0.3f - 0.01f) + 1e-5f;
        }
    }
}

extern "C" void kernel_launch(void* const* d_in, const int* in_sizes, int n_in,
                              void* d_out, int out_size, void* d_ws, size_t ws_size,
                              hipStream_t stream)
{
    const float* x     = (const float*)d_in[0];
    const float* ea    = (const float*)d_in[2];
    const float* lc_w1 = (const float*)d_in[6];
    const float* lc_b1 = (const float*)d_in[7];
    const float* lc_w2 = (const float*)d_in[8];
    const float* lc_b2 = (const float*)d_in[9];
    const float* lc_wl = (const float*)d_in[10];
    const float* lc_bl = (const float*)d_in[11];
    const float* ld_w1 = (const float*)d_in[12];
    const float* ld_b1 = (const float*)d_in[13];
    const float* ld_w2 = (const float*)d_in[14];
    const float* ld_b2 = (const float*)d_in[15];
    const float* g1_W  = (const float*)d_in[16];
    const float* g1_as = (const float*)d_in[17];
    const float* g1_ad = (const float*)d_in[18];
    const float* g1_We = (const float*)d_in[19];
    const float* g1_ae = (const float*)d_in[20];
    const float* g1_b  = (const float*)d_in[21];
    const float* g2_W  = (const float*)d_in[22];
    const float* g2_as = (const float*)d_in[23];
    const float* g2_ad = (const float*)d_in[24];
    const float* g2_We = (const float*)d_in[25];
    const float* g2_ae = (const float*)d_in[26];
    const float* g2_b  = (const float*)d_in[27];
    const float* g3_W  = (const float*)d_in[28];
    const float* g3_as = (const float*)d_in[29];
    const float* g3_ad = (const float*)d_in[30];
    const float* g3_We = (const float*)d_in[31];
    const float* g3_ae = (const float*)d_in[32];
    const float* g3_b  = (const float*)d_in[33];
    const float* fc1_W = (const float*)d_in[34];
    const float* fc1_b = (const float*)d_in[35];
    const float* fc2_W = (const float*)d_in[36];
    const float* fc2_b = (const float*)d_in[37];

    float* out = (float*)d_out;
    unsigned short* HA16 = (unsigned short*)d_ws;             // 8MB
    unsigned short* HB16 = HA16 + (size_t)NODES * FDIM;       // 8MB
    unsigned short* HC16 = HB16 + (size_t)NODES * FDIM;       // 8MB
    unsigned short* WT2  = HC16 + (size_t)NODES * FDIM;       // 128KB
    unsigned short* WT3  = WT2 + 256 * 256;                   // 128KB
    float* partial = (float*)(WT3 + 256 * 256);
    float* eamean  = partial + 256;

    ea_partial_kernel<<<256, 256, 0, stream>>>(ea, partial);
    ea_final_kernel<<<1, 256, 0, stream>>>(partial, eamean);
    wtrans_kernel<<<512, 256, 0, stream>>>(g2_W, g3_W, WT2, WT3);

    lidar_kernel<<<256, 256, 0, stream>>>(x, lc_w1, lc_b1, lc_w2, lc_b2, lc_wl, lc_bl,
                                          ld_w1, ld_b1, ld_w2, ld_b2, out);

    gat1_kernel<<<NGRAPH, 256, 0, stream>>>(x, g1_W, g1_as, g1_ad, g1_We, g1_ae,
                                            g1_b, ea, HA16);
    gat_mfma_kernel<<<NGRAPH, 256, 0, stream>>>(HA16, WT2, g2_as, g2_ad, g2_We, g2_ae,
                                                g2_b, ea, eamean, HB16);
    gat_mfma_kernel<<<NGRAPH, 256, 0, stream>>>(HB16, WT3, g3_as, g3_ad, g3_We, g3_ae,
                                                g3_b, ea, eamean, HC16);

    heads_kernel<<<NGRAPH, 256, 0, stream>>>(HC16, x, fc1_W, fc1_b, fc2_W, fc2_b, out);
}

// Round 6
// 157.655 us; speedup vs baseline: 1.9655x; 1.3089x over previous
//
#include <hip/hip_runtime.h>
#include <math.h>

#define NODES   16384
#define NGRAPH  1024
#define EDGES   245760
#define EPG     240
#define FDIM    256

#define OUT_MEAN  0
#define OUT_STD   24576
#define OUT_SCANS 49152
#define OUT_RECON 376832

typedef __attribute__((ext_vector_type(4))) short bf16x4;
typedef __attribute__((ext_vector_type(8))) short bf16x8;
typedef __attribute__((ext_vector_type(4))) float f32x4;

static __device__ __forceinline__ float lrelu02(float v){ return v > 0.f ? v : 0.2f*v; }

static __device__ __forceinline__ unsigned short f2bf(float f){
    unsigned u = __float_as_uint(f);
    u = (u + 0x7FFFu + ((u >> 16) & 1u)) >> 16;
    return (unsigned short)u;
}
static __device__ __forceinline__ float bf2f(unsigned short h){
    return __uint_as_float(((unsigned)h) << 16);
}

// ---------------- edge_attr mean (two-stage deterministic reduction) --------
__global__ __launch_bounds__(256) void ea_partial_kernel(const float* __restrict__ ea,
                                                         float* __restrict__ partial)
{
    __shared__ float red[256];
    const int tid = threadIdx.x;
    const int base = blockIdx.x * 960;
    float s = 0.f;
    for (int i = tid; i < 960; i += 256) s += ea[base + i];
    red[tid] = s; __syncthreads();
    for (int off = 128; off > 0; off >>= 1) {
        if (tid < off) red[tid] += red[tid + off];
        __syncthreads();
    }
    if (tid == 0) partial[blockIdx.x] = red[0];
}

__global__ __launch_bounds__(256) void ea_final_kernel(const float* __restrict__ partial,
                                                       float* __restrict__ mean_out)
{
    __shared__ float red[256];
    const int tid = threadIdx.x;
    red[tid] = partial[tid]; __syncthreads();
    for (int off = 128; off > 0; off >>= 1) {
        if (tid < off) red[tid] += red[tid + off];
        __syncthreads();
    }
    if (tid == 0) mean_out[0] = red[0] * (1.f / (float)EDGES);
}

// ---------------- W transpose + bf16 convert: WT[n][k] = bf16(W[k][n]) ------
__global__ __launch_bounds__(256) void wtrans_kernel(
    const float* __restrict__ W2, const float* __restrict__ W3,
    unsigned short* __restrict__ T2, unsigned short* __restrict__ T3)
{
    const int b = blockIdx.x;
    const float* W = (b < 256) ? W2 : W3;
    unsigned short* T = (b < 256) ? T2 : T3;
    const int n = b & 255, k = threadIdx.x;
    T[n * 256 + k] = f2bf(W[k * 256 + n]);
}

// ---------------- lidar encoder + recon (32 threads per node) ---------------
// Cooperative split within a 32-lane half-wave:
//  phase1: conv1+maxpool computed once -> pooled[10][16] in LDS
//          (lane's ic = lane&15 fixed -> 5 w1 weights in regs)
//  phase2: conv2: lane owns oc = lane, 48 w2 weights in VGPRs,
//          pooled columns broadcast-read from LDS, 3-slot sliding window
//  phase3: z via 32-lane shfl butterfly; hid; recon via LDS broadcast
__global__ __launch_bounds__(256) void lidar_kernel(
    const float* __restrict__ x,
    const float* __restrict__ w1, const float* __restrict__ b1,
    const float* __restrict__ w2, const float* __restrict__ b2,
    const float* __restrict__ wl, const float* __restrict__ bl,
    const float* __restrict__ dw1, const float* __restrict__ db1,
    const float* __restrict__ dw2, const float* __restrict__ db2,
    float* __restrict__ out)
{
    __shared__ float sc[8][25];        // padded scans
    __shared__ float pooled[8][160];   // [u][ic], u=0..9
    __shared__ float hid_lds[8][32];

    const int tid  = threadIdx.x;
    const int lane = tid & 31;
    const int nl   = tid >> 5;
    const int n    = blockIdx.x * 8 + nl;

    // stage scans + zero pads + emit scans output copy
    if (lane < 20) {
        const float v = x[n * 29 + lane];
        sc[nl][lane + 2] = v;
        out[OUT_SCANS + n * 20 + lane] = v;
    } else if (lane < 25) {
        const int pads[5] = {0, 1, 22, 23, 24};
        sc[nl][pads[lane - 20]] = 0.f;
    }
    __syncthreads();

    // conv1 + maxpool -> pooled (lane computes values v = q*32+lane, q<5)
    {
        const int ic = lane & 15;
        const int hi = lane >> 4;
        float w1r[5];
#pragma unroll
        for (int k = 0; k < 5; ++k) w1r[k] = w1[ic * 5 + k];
        const float b1r = b1[ic];
#pragma unroll
        for (int q = 0; q < 5; ++q) {
            const int u  = 2 * q + hi;
            const int p0 = 2 * u;
            float a = b1r, b = b1r;
#pragma unroll
            for (int k = 0; k < 5; ++k) {
                a += sc[nl][p0 + k] * w1r[k];
                b += sc[nl][p0 + 1 + k] * w1r[k];
            }
            pooled[nl][u * 16 + ic] = fmaxf(fmaxf(a, b), 0.f);
        }
    }
    __syncthreads();

    // conv2(+relu) + mean over 10 positions; lane owns oc = lane
    float macc = 0.f;
    {
        float wreg[48];   // w2[oc][ic][j]
#pragma unroll
        for (int i = 0; i < 12; ++i) {
            const float4 v4 = *(const float4*)&w2[lane * 48 + i * 4];
            wreg[i * 4 + 0] = v4.x; wreg[i * 4 + 1] = v4.y;
            wreg[i * 4 + 2] = v4.z; wreg[i * 4 + 3] = v4.w;
        }
        const float b2r = b2[lane];
        float pc[3][16];
#pragma unroll
        for (int i = 0; i < 4; ++i) {
            const float4 v0 = *(const float4*)&pooled[nl][0 * 16 + i * 4];
            const float4 v1 = *(const float4*)&pooled[nl][1 * 16 + i * 4];
            pc[0][i * 4 + 0] = v0.x; pc[0][i * 4 + 1] = v0.y; pc[0][i * 4 + 2] = v0.z; pc[0][i * 4 + 3] = v0.w;
            pc[1][i * 4 + 0] = v1.x; pc[1][i * 4 + 1] = v1.y; pc[1][i * 4 + 2] = v1.z; pc[1][i * 4 + 3] = v1.w;
            pc[2][i * 4 + 0] = 0.f;  pc[2][i * 4 + 1] = 0.f;  pc[2][i * 4 + 2] = 0.f;  pc[2][i * 4 + 3] = 0.f;
        }
#pragma unroll
        for (int t = 0; t < 10; ++t) {
            const int prev = (t + 2) % 3, cur = t % 3, nxt = (t + 1) % 3;
            if (t >= 1) {
                if (t + 1 <= 9) {
#pragma unroll
                    for (int i = 0; i < 4; ++i) {
                        const float4 v4 = *(const float4*)&pooled[nl][(t + 1) * 16 + i * 4];
                        pc[nxt][i * 4 + 0] = v4.x; pc[nxt][i * 4 + 1] = v4.y;
                        pc[nxt][i * 4 + 2] = v4.z; pc[nxt][i * 4 + 3] = v4.w;
                    }
                } else {
#pragma unroll
                    for (int ic = 0; ic < 16; ++ic) pc[nxt][ic] = 0.f;
                }
            }
            float v = b2r;
#pragma unroll
            for (int ic = 0; ic < 16; ++ic) {
                v += pc[prev][ic] * wreg[ic * 3 + 0]
                   + pc[cur][ic]  * wreg[ic * 3 + 1]
                   + pc[nxt][ic]  * wreg[ic * 3 + 2];
            }
            macc += fmaxf(v, 0.f);
        }
    }

    // tail: z (butterfly over the node's 32 lanes), hid, recon
    const float feat = macc * 0.1f;   // lane's channel of the pooled mean
    float z[5];
#pragma unroll
    for (int j = 0; j < 5; ++j) {
        float p = feat * wl[j * 32 + lane];
        p += __shfl_xor(p, 1);
        p += __shfl_xor(p, 2);
        p += __shfl_xor(p, 4);
        p += __shfl_xor(p, 8);
        p += __shfl_xor(p, 16);
        z[j] = fmaxf(bl[j] + p, 0.f);
    }
    float hv = db1[lane];
#pragma unroll
    for (int j = 0; j < 5; ++j) hv += z[j] * dw1[lane * 5 + j];
    hid_lds[nl][lane] = fmaxf(hv, 0.f);
    __syncthreads();

    if (lane < 20) {
        float acc = db2[lane];
#pragma unroll
        for (int k = 0; k < 32; ++k) acc += hid_lds[nl][k] * dw2[lane * 32 + k];
        out[OUT_RECON + n * 20 + lane] = acc;
    }
}

// ---------------- GAT layer 1 (K=6, VALU path, no self loops, bf16 out) -----
__global__ __launch_bounds__(256) void gat1_kernel(
    const float* __restrict__ hin,
    const float* __restrict__ W,       // (6, 256)
    const float* __restrict__ asrc, const float* __restrict__ adst,
    const float* __restrict__ We,  const float* __restrict__ ae,
    const float* __restrict__ bias,
    const float* __restrict__ ea,
    unsigned short* __restrict__ hout16)
{
    __shared__ float hs[16][6];
    __shared__ float xw[16][256];
    __shared__ float coef[16][16][8];   // [s][d][h]
    __shared__ float sals[16][8], sald[16][8];
    __shared__ float sasrc[256], sadst[256], sS[8];

    const int tid = threadIdx.x, g = blockIdx.x;

    if (tid < 96) { int i = tid / 6, k = tid % 6; hs[i][k] = hin[(g * 16 + i) * 29 + 20 + k]; }
    sasrc[tid] = asrc[tid];
    sadst[tid] = adst[tid];
    if (tid < 8) {
        float s = 0.f;
        for (int c = 0; c < 32; ++c) s += We[tid * 32 + c] * ae[tid * 32 + c];
        sS[tid] = s;
    }
    __syncthreads();

    {
        float acc[16];
#pragma unroll
        for (int i = 0; i < 16; ++i) acc[i] = 0.f;
#pragma unroll
        for (int k = 0; k < 6; ++k) {
            float w = W[k * 256 + tid];
#pragma unroll
            for (int i = 0; i < 16; ++i) acc[i] += hs[i][k] * w;
        }
#pragma unroll
        for (int i = 0; i < 16; ++i) xw[i][tid] = acc[i];
    }
    __syncthreads();

    if (tid < 128) {
        const int i = tid >> 3, h = tid & 7;
        float s1 = 0.f, s2 = 0.f;
#pragma unroll
        for (int c0 = 0; c0 < 32; c0 += 4) {
            const float4 v  = *(const float4*)&xw[i][h * 32 + c0];
            const float4 a1 = *(const float4*)&sasrc[h * 32 + c0];
            const float4 a2 = *(const float4*)&sadst[h * 32 + c0];
            s1 += v.x * a1.x + v.y * a1.y + v.z * a1.z + v.w * a1.w;
            s2 += v.x * a2.x + v.y * a2.y + v.z * a2.z + v.w * a2.w;
        }
        sals[i][h] = s1;
        sald[i][h] = s2;
    }
    __syncthreads();

    if (tid < 128) {
        const int d = tid >> 3, h = tid & 7;
        const float S = sS[h];
        const float aldv = sald[d][h];
        float alf[16];
        float m = -1e30f;
#pragma unroll
        for (int s = 0; s < 16; ++s) {
            float a;
            if (s == d) a = -1e30f;
            else {
                const int el = s * 15 + d - (d > s ? 1 : 0);
                a = lrelu02(sals[s][h] + aldv + ea[g * EPG + el] * S);
            }
            alf[s] = a;
            m = fmaxf(m, a);
        }
        float sum = 0.f;
#pragma unroll
        for (int s = 0; s < 16; ++s) { alf[s] = expf(alf[s] - m); sum += alf[s]; }
        const float r = 1.f / (sum + 1e-16f);
#pragma unroll
        for (int s = 0; s < 16; ++s) coef[s][d][h] = alf[s] * r;
    }
    __syncthreads();

    {
        const int h = tid >> 5;
        const float b = bias[tid];
        float o[16];
#pragma unroll
        for (int d = 0; d < 16; ++d) o[d] = b;
        for (int s = 0; s < 16; ++s) {
            const float xv = xw[s][tid];
#pragma unroll
            for (int d = 0; d < 16; ++d) o[d] += coef[s][d][h] * xv;
        }
        unsigned short* dst = hout16 + (size_t)g * 16 * 256 + tid;
#pragma unroll
        for (int d = 0; d < 16; ++d) dst[d * 256] = f2bf(fmaxf(o[d], 0.f));
    }
}

// ---------------- GAT layers 2/3: MFMA GEMM + fused attention ---------------
__global__ __launch_bounds__(256) void gat_mfma_kernel(
    const unsigned short* __restrict__ hin16,  // [N][256] bf16
    const unsigned short* __restrict__ WT16,   // [256][256] bf16, WT[n][k]
    const float* __restrict__ asrc, const float* __restrict__ adst,
    const float* __restrict__ We,  const float* __restrict__ ae,
    const float* __restrict__ bias,
    const float* __restrict__ ea,  const float* __restrict__ ea_mean,
    unsigned short* __restrict__ hout16)
{
    __shared__ char  hsb[8192];            // bf16 h tile [16][256], row-XOR swizzled
    __shared__ float xw[16][256];
    __shared__ float coef[16][16][8];      // [s][d][h]
    __shared__ float sals[16][8], sald[16][8];
    __shared__ float sasrc[256], sadst[256], sS[8];

    const int tid = threadIdx.x, g = blockIdx.x;
    const int lane = tid & 63, w = tid >> 6;

    {
        const char* src = (const char*)(hin16 + (size_t)g * 16 * 256);
        const int c0 = tid * 2;
#pragma unroll
        for (int c = c0; c < c0 + 2; ++c) {
            const int row = c >> 5;
            const int kb  = (c & 31) << 4;
            const float4 v = *(const float4*)(src + row * 512 + kb);
            *(float4*)(hsb + ((row * 512 + kb) ^ ((row & 7) << 4))) = v;
        }
    }
    sasrc[tid] = asrc[tid];
    sadst[tid] = adst[tid];
    if (tid < 8) {
        float s = 0.f;
        for (int c = 0; c < 32; ++c) s += We[tid * 32 + c] * ae[tid * 32 + c];
        sS[tid] = s;
    }
    __syncthreads();

    {
        f32x4 acc[4];
#pragma unroll
        for (int nt = 0; nt < 4; ++nt) acc[nt] = (f32x4){0.f, 0.f, 0.f, 0.f};
        const int arow = lane & 15;
        const int kg   = lane >> 4;
        const int aswz = (arow & 7) << 4;
        const char* wt = (const char*)WT16;
        for (int kk = 0; kk < 8; ++kk) {
            const int ab = arow * 512 + kk * 64 + kg * 8;
            const bf16x4 alo = *(const bf16x4*)(hsb + (ab ^ aswz));
            const bf16x4 ahi = *(const bf16x4*)(hsb + ((ab + 32) ^ aswz));
            const bf16x8 afrag = (bf16x8){alo[0], alo[1], alo[2], alo[3],
                                          ahi[0], ahi[1], ahi[2], ahi[3]};
#pragma unroll
            for (int nt = 0; nt < 4; ++nt) {
                const int ncol = w * 64 + nt * 16 + arow;
                const char* bp = wt + ncol * 512 + kk * 64 + kg * 8;
                const bf16x4 blo = *(const bf16x4*)(bp);
                const bf16x4 bhi = *(const bf16x4*)(bp + 32);
                const bf16x8 bfrag = (bf16x8){blo[0], blo[1], blo[2], blo[3],
                                              bhi[0], bhi[1], bhi[2], bhi[3]};
                acc[nt] = __builtin_amdgcn_mfma_f32_16x16x32_bf16(afrag, bfrag, acc[nt], 0, 0, 0);
            }
        }
#pragma unroll
        for (int nt = 0; nt < 4; ++nt) {
            const int col = w * 64 + nt * 16 + (lane & 15);
            const int r0  = (lane >> 4) * 4;
#pragma unroll
            for (int r = 0; r < 4; ++r) xw[r0 + r][col] = acc[nt][r];
        }
    }
    __syncthreads();

    if (tid < 128) {
        const int i = tid >> 3, h = tid & 7;
        float s1 = 0.f, s2 = 0.f;
#pragma unroll
        for (int c0 = 0; c0 < 32; c0 += 4) {
            const float4 v  = *(const float4*)&xw[i][h * 32 + c0];
            const float4 a1 = *(const float4*)&sasrc[h * 32 + c0];
            const float4 a2 = *(const float4*)&sadst[h * 32 + c0];
            s1 += v.x * a1.x + v.y * a1.y + v.z * a1.z + v.w * a1.w;
            s2 += v.x * a2.x + v.y * a2.y + v.z * a2.z + v.w * a2.w;
        }
        sals[i][h] = s1;
        sald[i][h] = s2;
    }
    __syncthreads();

    if (tid < 128) {
        const int d = tid >> 3, h = tid & 7;
        const float S = sS[h];
        const float aldv = sald[d][h];
        float alf[16];
        float m = -1e30f;
#pragma unroll
        for (int s = 0; s < 16; ++s) {
            float a;
            if (s == d) a = lrelu02(sals[s][h] + aldv + ea_mean[0] * S);
            else {
                const int el = s * 15 + d - (d > s ? 1 : 0);
                a = lrelu02(sals[s][h] + aldv + ea[g * EPG + el] * S);
            }
            alf[s] = a;
            m = fmaxf(m, a);
        }
        float sum = 0.f;
#pragma unroll
        for (int s = 0; s < 16; ++s) { alf[s] = expf(alf[s] - m); sum += alf[s]; }
        const float r = 1.f / (sum + 1e-16f);
#pragma unroll
        for (int s = 0; s < 16; ++s) coef[s][d][h] = alf[s] * r;
    }
    __syncthreads();

    {
        const int h = tid >> 5;
        const float b = bias[tid];
        float o[16];
#pragma unroll
        for (int d = 0; d < 16; ++d) o[d] = b;
        for (int s = 0; s < 16; ++s) {
            const float xv = xw[s][tid];
#pragma unroll
            for (int d = 0; d < 16; ++d) o[d] += coef[s][d][h] * xv;
        }
        unsigned short* dst = hout16 + (size_t)g * 16 * 256 + tid;
#pragma unroll
        for (int d = 0; d < 16; ++d) dst[d * 256] = f2bf(fmaxf(o[d], 0.f));
    }
}

// ---------------- pooling + actor heads (bf16 h input) ----------------------
__global__ __launch_bounds__(256) void heads_kernel(
    const unsigned short* __restrict__ Hb, const float* __restrict__ x,
    const float* __restrict__ fc1W, const float* __restrict__ fc1b,
    const float* __restrict__ fc2W, const float* __restrict__ fc2b,
    float* __restrict__ out)
{
    __shared__ float hsh[16][256];
    __shared__ float gem[256];
    __shared__ float lash[8][3];
    __shared__ float hidn[8][128];

    const int tid = threadIdx.x, g = blockIdx.x;
    for (int r = 0; r < 16; ++r) hsh[r][tid] = bf2f(Hb[(size_t)(g * 16 + r) * 256 + tid]);
    if (tid < 24) { int a = tid / 3, j = tid % 3; lash[a][j] = x[(g * 16 + a) * 29 + 26 + j]; }
    __syncthreads();
    {
        float s = 0.f;
#pragma unroll
        for (int r = 0; r < 16; ++r) s += hsh[r][tid];
        gem[tid] = s * (1.f / 16.f);
    }
    __syncthreads();

    {
        const int o = tid & 127;
        const int a0 = (tid >> 7) * 4;
        const float* wr = &fc1W[o * 515];
        float acc0 = fc1b[o], acc1 = acc0, acc2 = acc0, acc3 = acc0;
        for (int k = 0; k < 256; ++k) {
            const float w = wr[k];
            acc0 += w * hsh[a0 + 0][k];
            acc1 += w * hsh[a0 + 1][k];
            acc2 += w * hsh[a0 + 2][k];
            acc3 += w * hsh[a0 + 3][k];
        }
        float gacc = 0.f;
        for (int k = 0; k < 256; ++k) gacc += wr[256 + k] * gem[k];
#pragma unroll
        for (int j = 0; j < 3; ++j) {
            const float w = wr[512 + j];
            acc0 += w * lash[a0 + 0][j];
            acc1 += w * lash[a0 + 1][j];
            acc2 += w * lash[a0 + 2][j];
            acc3 += w * lash[a0 + 3][j];
        }
        acc0 += gacc; acc1 += gacc; acc2 += gacc; acc3 += gacc;
        hidn[a0 + 0][o] = fmaxf(acc0, 0.f);
        hidn[a0 + 1][o] = fmaxf(acc1, 0.f);
        hidn[a0 + 2][o] = fmaxf(acc2, 0.f);
        hidn[a0 + 3][o] = fmaxf(acc3, 0.f);
    }
    __syncthreads();

    if (tid < 48) {
        const int a = tid / 6, j = tid % 6;
        const float* wr = &fc2W[j * 128];
        float acc = fc2b[j];
#pragma unroll
        for (int k = 0; k < 128; ++k) acc += wr[k] * hidn[a][k];
        const int base = (g * 8 + a) * 3;
        if (j < 3) {
            const float lim = (j == 2) ? 3.1415927f : 1.0f;
            out[OUT_MEAN + base + j] = tanhf(acc) * lim;
        } else {
            const float sg = 1.f / (1.f + expf(-acc));
            out[OUT_STD + base + (j - 3)] = 0.01f + sg * (0.3f - 0.01f) + 1e-5f;
        }
    }
}

extern "C" void kernel_launch(void* const* d_in, const int* in_sizes, int n_in,
                              void* d_out, int out_size, void* d_ws, size_t ws_size,
                              hipStream_t stream)
{
    const float* x     = (const float*)d_in[0];
    const float* ea    = (const float*)d_in[2];
    const float* lc_w1 = (const float*)d_in[6];
    const float* lc_b1 = (const float*)d_in[7];
    const float* lc_w2 = (const float*)d_in[8];
    const float* lc_b2 = (const float*)d_in[9];
    const float* lc_wl = (const float*)d_in[10];
    const float* lc_bl = (const float*)d_in[11];
    const float* ld_w1 = (const float*)d_in[12];
    const float* ld_b1 = (const float*)d_in[13];
    const float* ld_w2 = (const float*)d_in[14];
    const float* ld_b2 = (const float*)d_in[15];
    const float* g1_W  = (const float*)d_in[16];
    const float* g1_as = (const float*)d_in[17];
    const float* g1_ad = (const float*)d_in[18];
    const float* g1_We = (const float*)d_in[19];
    const float* g1_ae = (const float*)d_in[20];
    const float* g1_b  = (const float*)d_in[21];
    const float* g2_W  = (const float*)d_in[22];
    const float* g2_as = (const float*)d_in[23];
    const float* g2_ad = (const float*)d_in[24];
    const float* g2_We = (const float*)d_in[25];
    const float* g2_ae = (const float*)d_in[26];
    const float* g2_b  = (const float*)d_in[27];
    const float* g3_W  = (const float*)d_in[28];
    const float* g3_as = (const float*)d_in[29];
    const float* g3_ad = (const float*)d_in[30];
    const float* g3_We = (const float*)d_in[31];
    const float* g3_ae = (const float*)d_in[32];
    const float* g3_b  = (const float*)d_in[33];
    const float* fc1_W = (const float*)d_in[34];
    const float* fc1_b = (const float*)d_in[35];
    const float* fc2_W = (const float*)d_in[36];
    const float* fc2_b = (const float*)d_in[37];

    float* out = (float*)d_out;
    unsigned short* HA16 = (unsigned short*)d_ws;             // 8MB
    unsigned short* HB16 = HA16 + (size_t)NODES * FDIM;       // 8MB
    unsigned short* HC16 = HB16 + (size_t)NODES * FDIM;       // 8MB
    unsigned short* WT2  = HC16 + (size_t)NODES * FDIM;       // 128KB
    unsigned short* WT3  = WT2 + 256 * 256;                   // 128KB
    float* partial = (float*)(WT3 + 256 * 256);
    float* eamean  = partial + 256;

    ea_partial_kernel<<<256, 256, 0, stream>>>(ea, partial);
    ea_final_kernel<<<1, 256, 0, stream>>>(partial, eamean);
    wtrans_kernel<<<512, 256, 0, stream>>>(g2_W, g3_W, WT2, WT3);

    lidar_kernel<<<2048, 256, 0, stream>>>(x, lc_w1, lc_b1, lc_w2, lc_b2, lc_wl, lc_bl,
                                           ld_w1, ld_b1, ld_w2, ld_b2, out);

    gat1_kernel<<<NGRAPH, 256, 0, stream>>>(x, g1_W, g1_as, g1_ad, g1_We, g1_ae,
                                            g1_b, ea, HA16);
    gat_mfma_kernel<<<NGRAPH, 256, 0, stream>>>(HA16, WT2, g2_as, g2_ad, g2_We, g2_ae,
                                                g2_b, ea, eamean, HB16);
    gat_mfma_kernel<<<NGRAPH, 256, 0, stream>>>(HB16, WT3, g3_as, g3_ad, g3_We, g3_ae,
                                                g3_b, ea, eamean, HC16);

    heads_kernel<<<NGRAPH, 256, 0, stream>>>(HC16, x, fc1_W, fc1_b, fc2_W, fc2_b, out);
}

// Round 7
// 139.893 us; speedup vs baseline: 2.2151x; 1.1270x over previous
//
#include <hip/hip_runtime.h>
#include <math.h>

#define NODES   16384
#define NGRAPH  1024
#define EDGES   245760
#define EPG     240
#define FDIM    256

#define OUT_MEAN  0
#define OUT_STD   24576
#define OUT_SCANS 49152
#define OUT_RECON 376832

typedef __attribute__((ext_vector_type(4))) short bf16x4;
typedef __attribute__((ext_vector_type(8))) short bf16x8;
typedef __attribute__((ext_vector_type(4))) float f32x4;

static __device__ __forceinline__ float lrelu02(float v){ return v > 0.f ? v : 0.2f*v; }

static __device__ __forceinline__ unsigned short f2bf(float f){
    unsigned u = __float_as_uint(f);
    u = (u + 0x7FFFu + ((u >> 16) & 1u)) >> 16;
    return (unsigned short)u;
}
static __device__ __forceinline__ float bf2f(unsigned short h){
    return __uint_as_float(((unsigned)h) << 16);
}

// ---------------- edge_attr mean (two-stage deterministic reduction) --------
__global__ __launch_bounds__(256) void ea_partial_kernel(const float* __restrict__ ea,
                                                         float* __restrict__ partial)
{
    __shared__ float red[256];
    const int tid = threadIdx.x;
    const int base = blockIdx.x * 960;
    float s = 0.f;
    for (int i = tid; i < 960; i += 256) s += ea[base + i];
    red[tid] = s; __syncthreads();
    for (int off = 128; off > 0; off >>= 1) {
        if (tid < off) red[tid] += red[tid + off];
        __syncthreads();
    }
    if (tid == 0) partial[blockIdx.x] = red[0];
}

__global__ __launch_bounds__(256) void ea_final_kernel(const float* __restrict__ partial,
                                                       float* __restrict__ mean_out)
{
    __shared__ float red[256];
    const int tid = threadIdx.x;
    red[tid] = partial[tid]; __syncthreads();
    for (int off = 128; off > 0; off >>= 1) {
        if (tid < off) red[tid] += red[tid + off];
        __syncthreads();
    }
    if (tid == 0) mean_out[0] = red[0] * (1.f / (float)EDGES);
}

// -------- weight prep: WT[n][k]=bf16(W[k][n]) for g2/g3; fc1WT[o][k] bf16 ----
__global__ __launch_bounds__(256) void wtrans_kernel(
    const float* __restrict__ W2, const float* __restrict__ W3,
    const float* __restrict__ F1,
    unsigned short* __restrict__ T2, unsigned short* __restrict__ T3,
    unsigned short* __restrict__ T1)
{
    const int b = blockIdx.x;
    if (b < 512) {
        const float* W = (b < 256) ? W2 : W3;
        unsigned short* T = (b < 256) ? T2 : T3;
        const int n = b & 255, k = threadIdx.x;
        T[n * 256 + k] = f2bf(W[k * 256 + n]);
    } else {
        const int o = b - 512;            // 0..127
        const int k0 = threadIdx.x * 2;   // 0..510
        T1[o * 512 + k0]     = f2bf(F1[o * 515 + k0]);
        T1[o * 512 + k0 + 1] = f2bf(F1[o * 515 + k0 + 1]);
    }
}

// ---------------- lidar encoder + recon (32 threads per node) ---------------
__global__ __launch_bounds__(256) void lidar_kernel(
    const float* __restrict__ x,
    const float* __restrict__ w1, const float* __restrict__ b1,
    const float* __restrict__ w2, const float* __restrict__ b2,
    const float* __restrict__ wl, const float* __restrict__ bl,
    const float* __restrict__ dw1, const float* __restrict__ db1,
    const float* __restrict__ dw2, const float* __restrict__ db2,
    float* __restrict__ out)
{
    __shared__ float sc[8][25];        // padded scans
    __shared__ float pooled[8][160];   // [u][ic], u=0..9
    __shared__ float hid_lds[8][32];

    const int tid  = threadIdx.x;
    const int lane = tid & 31;
    const int nl   = tid >> 5;
    const int n    = blockIdx.x * 8 + nl;

    if (lane < 20) {
        const float v = x[n * 29 + lane];
        sc[nl][lane + 2] = v;
        out[OUT_SCANS + n * 20 + lane] = v;
    } else if (lane < 25) {
        const int pads[5] = {0, 1, 22, 23, 24};
        sc[nl][pads[lane - 20]] = 0.f;
    }
    __syncthreads();

    {
        const int ic = lane & 15;
        const int hi = lane >> 4;
        float w1r[5];
#pragma unroll
        for (int k = 0; k < 5; ++k) w1r[k] = w1[ic * 5 + k];
        const float b1r = b1[ic];
#pragma unroll
        for (int q = 0; q < 5; ++q) {
            const int u  = 2 * q + hi;
            const int p0 = 2 * u;
            float a = b1r, b = b1r;
#pragma unroll
            for (int k = 0; k < 5; ++k) {
                a += sc[nl][p0 + k] * w1r[k];
                b += sc[nl][p0 + 1 + k] * w1r[k];
            }
            pooled[nl][u * 16 + ic] = fmaxf(fmaxf(a, b), 0.f);
        }
    }
    __syncthreads();

    float macc = 0.f;
    {
        float wreg[48];
#pragma unroll
        for (int i = 0; i < 12; ++i) {
            const float4 v4 = *(const float4*)&w2[lane * 48 + i * 4];
            wreg[i * 4 + 0] = v4.x; wreg[i * 4 + 1] = v4.y;
            wreg[i * 4 + 2] = v4.z; wreg[i * 4 + 3] = v4.w;
        }
        const float b2r = b2[lane];
        float pc[3][16];
#pragma unroll
        for (int i = 0; i < 4; ++i) {
            const float4 v0 = *(const float4*)&pooled[nl][0 * 16 + i * 4];
            const float4 v1 = *(const float4*)&pooled[nl][1 * 16 + i * 4];
            pc[0][i * 4 + 0] = v0.x; pc[0][i * 4 + 1] = v0.y; pc[0][i * 4 + 2] = v0.z; pc[0][i * 4 + 3] = v0.w;
            pc[1][i * 4 + 0] = v1.x; pc[1][i * 4 + 1] = v1.y; pc[1][i * 4 + 2] = v1.z; pc[1][i * 4 + 3] = v1.w;
            pc[2][i * 4 + 0] = 0.f;  pc[2][i * 4 + 1] = 0.f;  pc[2][i * 4 + 2] = 0.f;  pc[2][i * 4 + 3] = 0.f;
        }
#pragma unroll
        for (int t = 0; t < 10; ++t) {
            const int prev = (t + 2) % 3, cur = t % 3, nxt = (t + 1) % 3;
            if (t >= 1) {
                if (t + 1 <= 9) {
#pragma unroll
                    for (int i = 0; i < 4; ++i) {
                        const float4 v4 = *(const float4*)&pooled[nl][(t + 1) * 16 + i * 4];
                        pc[nxt][i * 4 + 0] = v4.x; pc[nxt][i * 4 + 1] = v4.y;
                        pc[nxt][i * 4 + 2] = v4.z; pc[nxt][i * 4 + 3] = v4.w;
                    }
                } else {
#pragma unroll
                    for (int ic = 0; ic < 16; ++ic) pc[nxt][ic] = 0.f;
                }
            }
            float v = b2r;
#pragma unroll
            for (int ic = 0; ic < 16; ++ic) {
                v += pc[prev][ic] * wreg[ic * 3 + 0]
                   + pc[cur][ic]  * wreg[ic * 3 + 1]
                   + pc[nxt][ic]  * wreg[ic * 3 + 2];
            }
            macc += fmaxf(v, 0.f);
        }
    }

    const float feat = macc * 0.1f;
    float z[5];
#pragma unroll
    for (int j = 0; j < 5; ++j) {
        float p = feat * wl[j * 32 + lane];
        p += __shfl_xor(p, 1);
        p += __shfl_xor(p, 2);
        p += __shfl_xor(p, 4);
        p += __shfl_xor(p, 8);
        p += __shfl_xor(p, 16);
        z[j] = fmaxf(bl[j] + p, 0.f);
    }
    float hv = db1[lane];
#pragma unroll
    for (int j = 0; j < 5; ++j) hv += z[j] * dw1[lane * 5 + j];
    hid_lds[nl][lane] = fmaxf(hv, 0.f);
    __syncthreads();

    if (lane < 20) {
        float acc = db2[lane];
#pragma unroll
        for (int k = 0; k < 32; ++k) acc += hid_lds[nl][k] * dw2[lane * 32 + k];
        out[OUT_RECON + n * 20 + lane] = acc;
    }
}

// ---------------- GAT layer 1 (K=6, VALU path, no self loops, bf16 out) -----
__global__ __launch_bounds__(256) void gat1_kernel(
    const float* __restrict__ hin,
    const float* __restrict__ W,       // (6, 256)
    const float* __restrict__ asrc, const float* __restrict__ adst,
    const float* __restrict__ We,  const float* __restrict__ ae,
    const float* __restrict__ bias,
    const float* __restrict__ ea,
    unsigned short* __restrict__ hout16)
{
    __shared__ float hs[16][6];
    __shared__ float xw[16][256];
    __shared__ float coef[16][16][8];   // [s][d][h]
    __shared__ float sals[16][8], sald[16][8];
    __shared__ float sasrc[256], sadst[256], sS[8];

    const int tid = threadIdx.x, g = blockIdx.x;

    if (tid < 96) { int i = tid / 6, k = tid % 6; hs[i][k] = hin[(g * 16 + i) * 29 + 20 + k]; }
    sasrc[tid] = asrc[tid];
    sadst[tid] = adst[tid];
    if (tid < 8) {
        float s = 0.f;
        for (int c = 0; c < 32; ++c) s += We[tid * 32 + c] * ae[tid * 32 + c];
        sS[tid] = s;
    }
    __syncthreads();

    {
        float acc[16];
#pragma unroll
        for (int i = 0; i < 16; ++i) acc[i] = 0.f;
#pragma unroll
        for (int k = 0; k < 6; ++k) {
            float w = W[k * 256 + tid];
#pragma unroll
            for (int i = 0; i < 16; ++i) acc[i] += hs[i][k] * w;
        }
#pragma unroll
        for (int i = 0; i < 16; ++i) xw[i][tid] = acc[i];
    }
    __syncthreads();

    if (tid < 128) {
        const int i = tid >> 3, h = tid & 7;
        float s1 = 0.f, s2 = 0.f;
#pragma unroll
        for (int c0 = 0; c0 < 32; c0 += 4) {
            const float4 v  = *(const float4*)&xw[i][h * 32 + c0];
            const float4 a1 = *(const float4*)&sasrc[h * 32 + c0];
            const float4 a2 = *(const float4*)&sadst[h * 32 + c0];
            s1 += v.x * a1.x + v.y * a1.y + v.z * a1.z + v.w * a1.w;
            s2 += v.x * a2.x + v.y * a2.y + v.z * a2.z + v.w * a2.w;
        }
        sals[i][h] = s1;
        sald[i][h] = s2;
    }
    __syncthreads();

    if (tid < 128) {
        const int d = tid >> 3, h = tid & 7;
        const float S = sS[h];
        const float aldv = sald[d][h];
        float alf[16];
        float m = -1e30f;
#pragma unroll
        for (int s = 0; s < 16; ++s) {
            float a;
            if (s == d) a = -1e30f;
            else {
                const int el = s * 15 + d - (d > s ? 1 : 0);
                a = lrelu02(sals[s][h] + aldv + ea[g * EPG + el] * S);
            }
            alf[s] = a;
            m = fmaxf(m, a);
        }
        float sum = 0.f;
#pragma unroll
        for (int s = 0; s < 16; ++s) { alf[s] = expf(alf[s] - m); sum += alf[s]; }
        const float r = 1.f / (sum + 1e-16f);
#pragma unroll
        for (int s = 0; s < 16; ++s) coef[s][d][h] = alf[s] * r;
    }
    __syncthreads();

    {
        const int h = tid >> 5;
        const float b = bias[tid];
        float o[16];
#pragma unroll
        for (int d = 0; d < 16; ++d) o[d] = b;
        for (int s = 0; s < 16; ++s) {
            const float xv = xw[s][tid];
#pragma unroll
            for (int d = 0; d < 16; ++d) o[d] += coef[s][d][h] * xv;
        }
        unsigned short* dst = hout16 + (size_t)g * 16 * 256 + tid;
#pragma unroll
        for (int d = 0; d < 16; ++d) dst[d * 256] = f2bf(fmaxf(o[d], 0.f));
    }
}

// ---------------- GAT layers 2/3: MFMA GEMM + fused attention ---------------
__global__ __launch_bounds__(256) void gat_mfma_kernel(
    const unsigned short* __restrict__ hin16,  // [N][256] bf16
    const unsigned short* __restrict__ WT16,   // [256][256] bf16, WT[n][k]
    const float* __restrict__ asrc, const float* __restrict__ adst,
    const float* __restrict__ We,  const float* __restrict__ ae,
    const float* __restrict__ bias,
    const float* __restrict__ ea,  const float* __restrict__ ea_mean,
    unsigned short* __restrict__ hout16)
{
    __shared__ char  hsb[8192];            // bf16 h tile [16][256], row-XOR swizzled
    __shared__ float xw[16][256];
    __shared__ float coef[16][16][8];      // [s][d][h]
    __shared__ float sals[16][8], sald[16][8];
    __shared__ float sasrc[256], sadst[256], sS[8];

    const int tid = threadIdx.x, g = blockIdx.x;
    const int lane = tid & 63, w = tid >> 6;

    {
        const char* src = (const char*)(hin16 + (size_t)g * 16 * 256);
        const int c0 = tid * 2;
#pragma unroll
        for (int c = c0; c < c0 + 2; ++c) {
            const int row = c >> 5;
            const int kb  = (c & 31) << 4;
            const float4 v = *(const float4*)(src + row * 512 + kb);
            *(float4*)(hsb + ((row * 512 + kb) ^ ((row & 7) << 4))) = v;
        }
    }
    sasrc[tid] = asrc[tid];
    sadst[tid] = adst[tid];
    if (tid < 8) {
        float s = 0.f;
        for (int c = 0; c < 32; ++c) s += We[tid * 32 + c] * ae[tid * 32 + c];
        sS[tid] = s;
    }
    __syncthreads();

    {
        f32x4 acc[4];
#pragma unroll
        for (int nt = 0; nt < 4; ++nt) acc[nt] = (f32x4){0.f, 0.f, 0.f, 0.f};
        const int arow = lane & 15;
        const int kg   = lane >> 4;
        const int aswz = (arow & 7) << 4;
        const char* wt = (const char*)WT16;
        for (int kk = 0; kk < 8; ++kk) {
            const int ab = arow * 512 + kk * 64 + kg * 8;
            const bf16x4 alo = *(const bf16x4*)(hsb + (ab ^ aswz));
            const bf16x4 ahi = *(const bf16x4*)(hsb + ((ab + 32) ^ aswz));
            const bf16x8 afrag = (bf16x8){alo[0], alo[1], alo[2], alo[3],
                                          ahi[0], ahi[1], ahi[2], ahi[3]};
#pragma unroll
            for (int nt = 0; nt < 4; ++nt) {
                const int ncol = w * 64 + nt * 16 + arow;
                const char* bp = wt + ncol * 512 + kk * 64 + kg * 8;
                const bf16x4 blo = *(const bf16x4*)(bp);
                const bf16x4 bhi = *(const bf16x4*)(bp + 32);
                const bf16x8 bfrag = (bf16x8){blo[0], blo[1], blo[2], blo[3],
                                              bhi[0], bhi[1], bhi[2], bhi[3]};
                acc[nt] = __builtin_amdgcn_mfma_f32_16x16x32_bf16(afrag, bfrag, acc[nt], 0, 0, 0);
            }
        }
#pragma unroll
        for (int nt = 0; nt < 4; ++nt) {
            const int col = w * 64 + nt * 16 + (lane & 15);
            const int r0  = (lane >> 4) * 4;
#pragma unroll
            for (int r = 0; r < 4; ++r) xw[r0 + r][col] = acc[nt][r];
        }
    }
    __syncthreads();

    if (tid < 128) {
        const int i = tid >> 3, h = tid & 7;
        float s1 = 0.f, s2 = 0.f;
#pragma unroll
        for (int c0 = 0; c0 < 32; c0 += 4) {
            const float4 v  = *(const float4*)&xw[i][h * 32 + c0];
            const float4 a1 = *(const float4*)&sasrc[h * 32 + c0];
            const float4 a2 = *(const float4*)&sadst[h * 32 + c0];
            s1 += v.x * a1.x + v.y * a1.y + v.z * a1.z + v.w * a1.w;
            s2 += v.x * a2.x + v.y * a2.y + v.z * a2.z + v.w * a2.w;
        }
        sals[i][h] = s1;
        sald[i][h] = s2;
    }
    __syncthreads();

    if (tid < 128) {
        const int d = tid >> 3, h = tid & 7;
        const float S = sS[h];
        const float aldv = sald[d][h];
        float alf[16];
        float m = -1e30f;
#pragma unroll
        for (int s = 0; s < 16; ++s) {
            float a;
            if (s == d) a = lrelu02(sals[s][h] + aldv + ea_mean[0] * S);
            else {
                const int el = s * 15 + d - (d > s ? 1 : 0);
                a = lrelu02(sals[s][h] + aldv + ea[g * EPG + el] * S);
            }
            alf[s] = a;
            m = fmaxf(m, a);
        }
        float sum = 0.f;
#pragma unroll
        for (int s = 0; s < 16; ++s) { alf[s] = expf(alf[s] - m); sum += alf[s]; }
        const float r = 1.f / (sum + 1e-16f);
#pragma unroll
        for (int s = 0; s < 16; ++s) coef[s][d][h] = alf[s] * r;
    }
    __syncthreads();

    {
        const int h = tid >> 5;
        const float b = bias[tid];
        float o[16];
#pragma unroll
        for (int d = 0; d < 16; ++d) o[d] = b;
        for (int s = 0; s < 16; ++s) {
            const float xv = xw[s][tid];
#pragma unroll
            for (int d = 0; d < 16; ++d) o[d] += coef[s][d][h] * xv;
        }
        unsigned short* dst = hout16 + (size_t)g * 16 * 256 + tid;
#pragma unroll
        for (int d = 0; d < 16; ++d) dst[d * 256] = f2bf(fmaxf(o[d], 0.f));
    }
}

// ------- pooling + actor heads: block = 2 graphs, fc1 via MFMA --------------
// M=16 agent rows (2 graphs x 8 agents), K=512 ([aemb|gemb] bf16), N=128.
// Same fragment maps / XOR swizzle as gat_mfma; la(3) + bias in fp32 epilogue.
__global__ __launch_bounds__(256) void heads_kernel(
    const unsigned short* __restrict__ Hb, const float* __restrict__ x,
    const unsigned short* __restrict__ fc1WT,  // [128][512] bf16
    const float* __restrict__ fc1W,            // (128,515) fp32 (la cols)
    const float* __restrict__ fc1b,
    const float* __restrict__ fc2W, const float* __restrict__ fc2b,
    float* __restrict__ out)
{
    __shared__ char  comb[16384] __attribute__((aligned(16)));  // [16][1024B] swizzled
    __shared__ float gemb[2][256];
    __shared__ float lash[16][3];
    __shared__ float hidn[16][128];

    const int tid = threadIdx.x, bid = blockIdx.x;
    const int lane = tid & 63, w = tid >> 6;
    const int g0 = bid * 2;

    // gemb for both graphs (fp32 sums of bf16 h, ushort2 loads)
    {
        const int gg = tid >> 7;
        const int c2 = (tid & 127) * 2;
        const size_t base = (size_t)(g0 + gg) * 16 * 256 + c2;
        float s0 = 0.f, s1 = 0.f;
#pragma unroll
        for (int r = 0; r < 16; ++r) {
            const unsigned v = *(const unsigned*)(Hb + base + r * 256);
            s0 += __uint_as_float((v & 0xFFFFu) << 16);
            s1 += __uint_as_float(v & 0xFFFF0000u);
        }
        gemb[gg][c2]     = s0 * (1.f / 16.f);
        gemb[gg][c2 + 1] = s1 * (1.f / 16.f);
    }
    if (tid < 48) {
        const int a = tid / 3, j = tid % 3;
        const int g = g0 + (a >> 3);
        lash[a][j] = x[(g * 16 + (a & 7)) * 29 + 26 + j];
    }
    __syncthreads();

    // stage comb A-tile: rows 0-7 = g0 agents, 8-15 = g1 agents; cols [h|gemb]
#pragma unroll
    for (int i = 0; i < 4; ++i) {
        const int c   = i * 256 + tid;      // chunk 0..1023 (16B each)
        const int row = c >> 6;
        const int kb  = c & 63;
        char* dst = comb + ((row * 1024 + kb * 16) ^ ((row & 7) << 4));
        if (kb < 32) {
            const int node = (row < 8) ? (g0 * 16 + row) : ((g0 + 1) * 16 + row - 8);
            *(float4*)dst = *(const float4*)((const char*)Hb + (size_t)node * 512 + kb * 16);
        } else {
            const float* gs = &gemb[row >> 3][(kb - 32) * 8];
            unsigned short tmp[8];
#pragma unroll
            for (int q = 0; q < 8; ++q) tmp[q] = f2bf(gs[q]);
            *(float4*)dst = *(const float4*)tmp;
        }
    }
    __syncthreads();

    // MFMA: wave w covers output cols w*32 .. w*32+31
    {
        f32x4 acc[2];
        acc[0] = (f32x4){0.f, 0.f, 0.f, 0.f};
        acc[1] = (f32x4){0.f, 0.f, 0.f, 0.f};
        const int arow = lane & 15;
        const int kg   = lane >> 4;
        const int aswz = (arow & 7) << 4;
        for (int kk = 0; kk < 16; ++kk) {
            const int ab = arow * 1024 + kk * 64 + kg * 8;
            const bf16x4 alo = *(const bf16x4*)(comb + (ab ^ aswz));
            const bf16x4 ahi = *(const bf16x4*)(comb + ((ab + 32) ^ aswz));
            const bf16x8 afrag = (bf16x8){alo[0], alo[1], alo[2], alo[3],
                                          ahi[0], ahi[1], ahi[2], ahi[3]};
#pragma unroll
            for (int nt = 0; nt < 2; ++nt) {
                const int o = w * 32 + nt * 16 + arow;
                const char* bp = (const char*)fc1WT + o * 1024 + kk * 64 + kg * 8;
                const bf16x4 blo = *(const bf16x4*)(bp);
                const bf16x4 bhi = *(const bf16x4*)(bp + 32);
                const bf16x8 bfrag = (bf16x8){blo[0], blo[1], blo[2], blo[3],
                                              bhi[0], bhi[1], bhi[2], bhi[3]};
                acc[nt] = __builtin_amdgcn_mfma_f32_16x16x32_bf16(afrag, bfrag, acc[nt], 0, 0, 0);
            }
        }
        // epilogue: + la @ W_la + bias, relu -> hidn
#pragma unroll
        for (int nt = 0; nt < 2; ++nt) {
            const int o = w * 32 + nt * 16 + (lane & 15);
            const float wl0 = fc1W[o * 515 + 512];
            const float wl1 = fc1W[o * 515 + 513];
            const float wl2 = fc1W[o * 515 + 514];
            const float b   = fc1b[o];
            const int r0 = (lane >> 4) * 4;
#pragma unroll
            for (int r = 0; r < 4; ++r) {
                const int row = r0 + r;
                float v = acc[nt][r] + b
                        + lash[row][0] * wl0 + lash[row][1] * wl1 + lash[row][2] * wl2;
                hidn[row][o] = fmaxf(v, 0.f);
            }
        }
    }
    __syncthreads();

    // fc2 + output transforms (16 agents x 6 outputs)
    if (tid < 96) {
        const int a = tid / 6, j = tid % 6;
        const float* wr = &fc2W[j * 128];
        float acc = fc2b[j];
#pragma unroll
        for (int k = 0; k < 128; ++k) acc += wr[k] * hidn[a][k];
        const int g = g0 + (a >> 3);
        const int base = (g * 8 + (a & 7)) * 3;
        if (j < 3) {
            const float lim = (j == 2) ? 3.1415927f : 1.0f;
            out[OUT_MEAN + base + j] = tanhf(acc) * lim;
        } else {
            const float sg = 1.f / (1.f + expf(-acc));
            out[OUT_STD + base + (j - 3)] = 0.01f + sg * (0.3f - 0.01f) + 1e-5f;
        }
    }
}

extern "C" void kernel_launch(void* const* d_in, const int* in_sizes, int n_in,
                              void* d_out, int out_size, void* d_ws, size_t ws_size,
                              hipStream_t stream)
{
    const float* x     = (const float*)d_in[0];
    const float* ea    = (const float*)d_in[2];
    const float* lc_w1 = (const float*)d_in[6];
    const float* lc_b1 = (const float*)d_in[7];
    const float* lc_w2 = (const float*)d_in[8];
    const float* lc_b2 = (const float*)d_in[9];
    const float* lc_wl = (const float*)d_in[10];
    const float* lc_bl = (const float*)d_in[11];
    const float* ld_w1 = (const float*)d_in[12];
    const float* ld_b1 = (const float*)d_in[13];
    const float* ld_w2 = (const float*)d_in[14];
    const float* ld_b2 = (const float*)d_in[15];
    const float* g1_W  = (const float*)d_in[16];
    const float* g1_as = (const float*)d_in[17];
    const float* g1_ad = (const float*)d_in[18];
    const float* g1_We = (const float*)d_in[19];
    const float* g1_ae = (const float*)d_in[20];
    const float* g1_b  = (const float*)d_in[21];
    const float* g2_W  = (const float*)d_in[22];
    const float* g2_as = (const float*)d_in[23];
    const float* g2_ad = (const float*)d_in[24];
    const float* g2_We = (const float*)d_in[25];
    const float* g2_ae = (const float*)d_in[26];
    const float* g2_b  = (const float*)d_in[27];
    const float* g3_W  = (const float*)d_in[28];
    const float* g3_as = (const float*)d_in[29];
    const float* g3_ad = (const float*)d_in[30];
    const float* g3_We = (const float*)d_in[31];
    const float* g3_ae = (const float*)d_in[32];
    const float* g3_b  = (const float*)d_in[33];
    const float* fc1_W = (const float*)d_in[34];
    const float* fc1_b = (const float*)d_in[35];
    const float* fc2_W = (const float*)d_in[36];
    const float* fc2_b = (const float*)d_in[37];

    float* out = (float*)d_out;
    unsigned short* HA16 = (unsigned short*)d_ws;             // 8MB
    unsigned short* HB16 = HA16 + (size_t)NODES * FDIM;       // 8MB
    unsigned short* HC16 = HB16 + (size_t)NODES * FDIM;       // 8MB
    unsigned short* WT2  = HC16 + (size_t)NODES * FDIM;       // 128KB
    unsigned short* WT3  = WT2 + 256 * 256;                   // 128KB
    unsigned short* FT1  = WT3 + 256 * 256;                   // 128KB
    float* partial = (float*)(FT1 + 128 * 512);
    float* eamean  = partial + 256;

    ea_partial_kernel<<<256, 256, 0, stream>>>(ea, partial);
    ea_final_kernel<<<1, 256, 0, stream>>>(partial, eamean);
    wtrans_kernel<<<640, 256, 0, stream>>>(g2_W, g3_W, fc1_W, WT2, WT3, FT1);

    lidar_kernel<<<2048, 256, 0, stream>>>(x, lc_w1, lc_b1, lc_w2, lc_b2, lc_wl, lc_bl,
                                           ld_w1, ld_b1, ld_w2, ld_b2, out);

    gat1_kernel<<<NGRAPH, 256, 0, stream>>>(x, g1_W, g1_as, g1_ad, g1_We, g1_ae,
                                            g1_b, ea, HA16);
    gat_mfma_kernel<<<NGRAPH, 256, 0, stream>>>(HA16, WT2, g2_as, g2_ad, g2_We, g2_ae,
                                                g2_b, ea, eamean, HB16);
    gat_mfma_kernel<<<NGRAPH, 256, 0, stream>>>(HB16, WT3, g3_as, g3_ad, g3_We, g3_ae,
                                                g3_b, ea, eamean, HC16);

    heads_kernel<<<512, 256, 0, stream>>>(HC16, x, FT1, fc1_W, fc1_b, fc2_W, fc2_b, out);
}